// Round 15
// baseline (1712.260 us; speedup 1.0000x reference)
//
#include <hip/hip_runtime.h>
#include <math.h>

typedef unsigned short u16;
typedef unsigned int   u32;
typedef __attribute__((ext_vector_type(8))) short short8;
typedef __attribute__((ext_vector_type(4))) float f32x4;

#define NBATCH 1024
#define NT 64
#define OC 580
#define RB 16            // batch rows per scan block
#define SCAN_BLOCKS (NBATCH / RB)
#define SX 232           // bf16 LDS row stride
#define SF 212           // f32 LDS row stride

// packed bf16 weight fragments (1024-u16 spacing, 512 used) in d_ws (u16 units)
#define P_WI    0        // [tt13][ks2]
#define P_WIH   26624    // [(g*13+tt)][ks7]
#define P_WHH   306176
#define P_WQ1   585728   // [tt13][ks7]
#define P_WQ2   678912   // [tt4][ks7]
#define P_EB    707584   // [ks32][tt13]
#define P_WP1   1133568  // [ks7][tt13]
#define P_WP2   1226752  // [ks7][tt4]
#define P_TOTAL 1255424

__device__ __forceinline__ float elu_f(float x) { return x > 0.f ? x : __expf(x) - 1.f; }
__device__ __forceinline__ float sig_f(float x) { return __fdividef(1.f, 1.f + __expf(-x)); }
__device__ __forceinline__ float sp_f(float x)  { return x > 20.f ? x : log1pf(__expf(x)); }
__device__ __forceinline__ float tanh_f(float x) {   // fast tanh
    float ax = fabsf(x); ax = ax > 10.f ? 10.f : ax;
    float e = __expf(2.f * ax);
    float t = __fdividef(e - 1.f, e + 1.f);
    return copysignf(t, x);
}

// LDS-only barrier: no vmcnt(0) drain (scan has NO intra-kernel global RAW).
__device__ __forceinline__ void bar_lds() {
    __builtin_amdgcn_sched_barrier(0);
    asm volatile("s_waitcnt lgkmcnt(0)" ::: "memory");
    __builtin_amdgcn_s_barrier();
    __builtin_amdgcn_sched_barrier(0);
}

__device__ __forceinline__ u16 f2b(float f) {   // f32 -> bf16 RNE
    union { float f; u32 u; } v; v.f = f;
    u32 r = (v.u + 0x7fffu + ((v.u >> 16) & 1u)) >> 16;
    return (u16)r;
}

__device__ __forceinline__ short8 pack8(float4 v0, float4 v1) {
    short8 r;
    r[0] = (short)f2b(v0.x); r[1] = (short)f2b(v0.y);
    r[2] = (short)f2b(v0.z); r[3] = (short)f2b(v0.w);
    r[4] = (short)f2b(v1.x); r[5] = (short)f2b(v1.y);
    r[6] = (short)f2b(v1.z); r[7] = (short)f2b(v1.w);
    return r;
}

#define MFMA(a, b, c) __builtin_amdgcn_mfma_f32_16x16x32_bf16((a), (b), (c), 0, 0, 0)

// ---------------------------------------------------------------------------
// prep: pack weights to bf16 MFMA B-fragment order:
// frag[lane][e] = W[n0 + (lane&15)][k0 + (lane>>4)*8 + e]  (0-padded)
// ---------------------------------------------------------------------------
__global__ __launch_bounds__(256) void prep_pack(
    const float* __restrict__ Wi, const float* __restrict__ W_ih,
    const float* __restrict__ W_hh, const float* __restrict__ Wq1,
    const float* __restrict__ Wq2, const float* __restrict__ Wp1,
    const float* __restrict__ Wp2, u16* __restrict__ wp)
{
    for (size_t r = (size_t)blockIdx.x * 256 + threadIdx.x; r < P_TOTAL;
         r += (size_t)gridDim.x * 256) {
        float val = 0.f;
        if (r < P_WIH) {                           // Wi: [200 x 36]
            int tile = r / 1024, lane = (r % 1024) / 8, el = r % 8;
            int tt = tile / 2, ks = tile % 2;
            int j = tt * 16 + (lane & 15), k = ks * 32 + (lane >> 4) * 8 + el;
            if (j < 200 && k < 36 && lane < 64) val = Wi[j * 36 + k];
        } else if (r < P_WHH) {                    // W_ih
            size_t q = r - P_WIH;
            int tile = q / 1024, lane = (q % 1024) / 8, el = q % 8;
            int g = tile / 91, rem = tile % 91, tt = rem / 7, ks = rem % 7;
            int j = tt * 16 + (lane & 15), k = ks * 32 + (lane >> 4) * 8 + el;
            if (j < 200 && k < 200 && lane < 64) val = W_ih[(size_t)(g * 200 + j) * 200 + k];
        } else if (r < P_WQ1) {                    // W_hh
            size_t q = r - P_WHH;
            int tile = q / 1024, lane = (q % 1024) / 8, el = q % 8;
            int g = tile / 91, rem = tile % 91, tt = rem / 7, ks = rem % 7;
            int j = tt * 16 + (lane & 15), k = ks * 32 + (lane >> 4) * 8 + el;
            if (j < 200 && k < 200 && lane < 64) val = W_hh[(size_t)(g * 200 + j) * 200 + k];
        } else if (r < P_WQ2) {                    // Wq1[:, :200]
            size_t q = r - P_WQ1;
            int tile = q / 1024, lane = (q % 1024) / 8, el = q % 8;
            int tt = tile / 7, ks = tile % 7;
            int j = tt * 16 + (lane & 15), k = ks * 32 + (lane >> 4) * 8 + el;
            if (j < 200 && k < 200 && lane < 64) val = Wq1[(size_t)j * 1224 + k];
        } else if (r < P_EB) {                     // Wq2: [60 x 200]
            size_t q = r - P_WQ2;
            int tile = q / 1024, lane = (q % 1024) / 8, el = q % 8;
            int tt = tile / 7, ks = tile % 7;
            int j = tt * 16 + (lane & 15), k = ks * 32 + (lane >> 4) * 8 + el;
            if (j < 60 && k < 200 && lane < 64) val = Wq2[(size_t)j * 200 + k];
        } else if (r < P_WP1) {                    // epre B: Wq1[:,200:1224]
            size_t q = r - P_EB;
            int tile = q / 1024, lane = (q % 1024) / 8, el = q % 8;
            int ks = tile / 13, tt = tile % 13;
            int j = tt * 16 + (lane & 15), k = ks * 32 + (lane >> 4) * 8 + el;
            if (j < 200 && lane < 64) val = Wq1[(size_t)j * 1224 + 200 + k];
        } else if (r < P_WP2) {                    // Wp1: [200 x 200]
            size_t q = r - P_WP1;
            int tile = q / 1024, lane = (q % 1024) / 8, el = q % 8;
            int ks = tile / 13, tt = tile % 13;
            int j = tt * 16 + (lane & 15), k = ks * 32 + (lane >> 4) * 8 + el;
            if (j < 200 && k < 200 && lane < 64) val = Wp1[(size_t)j * 200 + k];
        } else {                                   // Wp2: [60 x 200]
            size_t q = r - P_WP2;
            int tile = q / 1024, lane = (q % 1024) / 8, el = q % 8;
            int ks = tile / 4, tt = tile % 4;
            int j = tt * 16 + (lane & 15), k = ks * 32 + (lane >> 4) * 8 + el;
            if (j < 60 && k < 200 && lane < 64) val = Wp2[(size_t)j * 200 + k];
        }
        wp[r] = f2b(val);
    }
}

// ---------------------------------------------------------------------------
// Epre (MFMA): out[bt*580+290+j] = embed[bt] . Wq1[j][200:] + bq1[j]
// ---------------------------------------------------------------------------
__global__ __launch_bounds__(512) void epre_mfma(
    const float* __restrict__ embed, const u16* __restrict__ wp,
    const float* __restrict__ bq1, float* __restrict__ out)
{
    const int tid = threadIdx.x;
    const int wv = tid >> 6, ln = tid & 63;
    const int arow = ln & 15, kgrp = ln >> 4;
    const int m0 = blockIdx.x * 256 + wv * 32;

    f32x4 acc[2][13];
    #pragma unroll
    for (int tt = 0; tt < 13; ++tt) {
        const int j = tt * 16 + arow;
        const float bv = (j < 200) ? bq1[j] : 0.f;
        acc[0][tt] = (f32x4){bv, bv, bv, bv};
        acc[1][tt] = acc[0][tt];
    }
    const float* e0 = &embed[(size_t)(m0 + arow) * 1024 + kgrp * 8];
    const float* e1 = e0 + (size_t)16 * 1024;

    for (int ks = 0; ks < 32; ++ks) {
        short8 a0, a1;
        {
            float4 v0 = *(const float4*)(e0 + ks * 32);
            float4 v1 = *(const float4*)(e0 + ks * 32 + 4);
            a0 = pack8(v0, v1);
            float4 w0 = *(const float4*)(e1 + ks * 32);
            float4 w1 = *(const float4*)(e1 + ks * 32 + 4);
            a1 = pack8(w0, w1);
        }
        const u16* bp = &wp[P_EB + (size_t)ks * 13 * 1024 + (size_t)ln * 8];
        #pragma unroll
        for (int tt = 0; tt < 13; ++tt) {
            short8 b = *(const short8*)(bp + (size_t)tt * 1024);
            acc[0][tt] = MFMA(a0, b, acc[0][tt]);
            acc[1][tt] = MFMA(a1, b, acc[1][tt]);
        }
    }
    #pragma unroll
    for (int f = 0; f < 2; ++f) {
        const size_t rbase = (size_t)(m0 + f * 16 + kgrp * 4);
        #pragma unroll
        for (int tt = 0; tt < 13; ++tt) {
            const int j = tt * 16 + arow;
            if (j < 200) {
                #pragma unroll
                for (int e = 0; e < 4; ++e)
                    out[(rbase + e) * OC + 290 + j] = acc[f][tt][e];
            }
        }
    }
}

// ---------------------------------------------------------------------------
// MFMA scan: 64 blocks x 16 batch rows, 512 threads (8 waves).
// r12 base (LDS-only barriers, fast tanh) with:
//  - phase B owns whole tiles (all 3 gates) -> in-register GRU combine
//    (no gate LDS arrays, one less barrier)
//  - Epre(t+1)/action(t+1) staged by light waves (5-7) INSIDE phase B into
//    double-buffered s_ep (issue-early/write-late, same phase, no cross-
//    barrier register holding). 5 barriers/step.
// ---------------------------------------------------------------------------
__global__ __launch_bounds__(512, 2) void scan_mfma(
    const float* __restrict__ action, const float* __restrict__ noise_post,
    const float* __restrict__ b_ih, const float* __restrict__ b_hh,
    const float* __restrict__ bi, const float* __restrict__ bq2,
    const u16* __restrict__ wp, float* __restrict__ out)
{
    __shared__ u16   s_in0[RB][72];           // [stoch30 | act6 | 0pad], K=64 used
    __shared__ u16   s_x[RB][SX];             // x bf16
    __shared__ u16   s_db[RB][SX];            // deter bf16 (MFMA shadow)
    __shared__ u16   s_hq[RB][SX];            // hq bf16
    __shared__ float s_df[RB][200];           // deter fp32 carry
    __shared__ float s_ep[2][RB][SF];         // Epre staged fp32 (double buffer)
    __shared__ float s_q[RB][64];
    __shared__ float s_bih[3][208], s_bhh[3][208], s_bi[208], s_bq2[64];

    const int tid  = threadIdx.x;
    const int wv   = tid >> 6, ln = tid & 63;
    const int arow = ln & 15, kgrp = ln >> 4;
    const int b0   = blockIdx.x * RB;

    // init: zero bf16 activations (incl. K-pads) + s_ep + s_df, stage biases
    { u32* z = (u32*)s_in0; for (int i = tid; i < RB*72/2;  i += 512) z[i] = 0; }
    { u32* z = (u32*)s_x;   for (int i = tid; i < RB*SX/2;  i += 512) z[i] = 0; }
    { u32* z = (u32*)s_db;  for (int i = tid; i < RB*SX/2;  i += 512) z[i] = 0; }
    { u32* z = (u32*)s_hq;  for (int i = tid; i < RB*SX/2;  i += 512) z[i] = 0; }
    { float* z = (float*)s_ep; for (int i = tid; i < 2*RB*SF; i += 512) z[i] = 0.f; }
    { float* z = (float*)s_df; for (int i = tid; i < RB*200; i += 512) z[i] = 0.f; }
    for (int i = tid; i < 3 * 208; i += 512) {
        int g = i / 208, j = i % 208;
        s_bih[g][j] = j < 200 ? b_ih[g * 200 + j] : 0.f;
        s_bhh[g][j] = j < 200 ? b_hh[g * 200 + j] : 0.f;
    }
    for (int i = tid; i < 208; i += 512) s_bi[i] = i < 200 ? bi[i] : 0.f;
    if (tid < 64) s_bq2[tid] = tid < 60 ? bq2[tid] : 0.f;
    __syncthreads();   // init complete before prologue staging

    // ---- prologue: stage Epre(0) + action(0) ----
    for (int idx = tid; idx < RB * 200; idx += 512) {
        int i = idx / 200, j = idx - i * 200;
        s_ep[0][i][j] = out[((size_t)(b0 + i) * NT + 0) * OC + 290 + j];
    }
    if (tid < 96) {
        int ia = tid / 6, ca = tid - (tid / 6) * 6;
        s_in0[ia][30 + ca] = f2b(action[((size_t)(b0 + ia) * NT + 0) * 6 + ca]);
    }
    __syncthreads();

    // tile ownership: t0 = wv (always), t1 = wv+8 (wv<5)
    const int  t0 = wv, t1 = wv + 8;
    const bool has2 = (t1 < 13);
    const int  j0 = t0 * 16 + arow;
    const int  j1 = t1 * 16 + arow;
    const bool lightw = (wv >= 5);
    const int  ll = (wv - 5) * 64 + ln;   // 0..191 on light waves

    for (int t = 0; t < NT; ++t) {
        const int p0 = t & 1, p1 = (t + 1) & 1;
        const bool pN = (t + 1 < NT);

        // ---- phase A: x = elu([stoch|act] @ Wi^T + bi) ----
        for (int tt = wv; tt < 13; tt += 8) {
            float bv = s_bi[tt * 16 + arow];
            f32x4 acc = {bv, bv, bv, bv};
            #pragma unroll
            for (int ks = 0; ks < 2; ++ks) {
                short8 af = *(const short8*)&s_in0[arow][ks * 32 + kgrp * 8];
                short8 wf = *(const short8*)&wp[P_WI + (size_t)(tt * 2 + ks) * 1024 + ln * 8];
                acc = MFMA(af, wf, acc);
            }
            #pragma unroll
            for (int e = 0; e < 4; ++e)
                s_x[kgrp * 4 + e][tt * 16 + arow] = f2b(elu_f(acc[e]));
        }
        bar_lds();

        // ---- merged phase B: gates (full tile ownership) + in-register
        //      combine + light-wave staging of Epre(t+1)/action(t+1) ----
        {
            // light waves: issue next-step staging loads early
            float epv[17]; float av = 0.f;
            if (lightw && pN) {
                #pragma unroll
                for (int k = 0; k < 17; ++k) {
                    int idx = ll + k * 192;
                    if (idx < RB * 200) {
                        int i = idx / 200, j = idx - i * 200;
                        epv[k] = out[((size_t)(b0 + i) * NT + (t + 1)) * OC + 290 + j];
                    }
                }
                if (ll < 96)
                    av = action[((size_t)(b0 + ll / 6) * NT + (t + 1)) * 6 + (ll % 6)];
            }

            f32x4 gi0[3], gh0[3], gi1[3], gh1[3];
            #pragma unroll
            for (int g = 0; g < 3; ++g) {
                float b1 = s_bih[g][j0], b2 = s_bhh[g][j0];
                gi0[g] = (f32x4){b1, b1, b1, b1};
                gh0[g] = (f32x4){b2, b2, b2, b2};
                float c1 = has2 ? s_bih[g][j1] : 0.f;
                float c2 = has2 ? s_bhh[g][j1] : 0.f;
                gi1[g] = (f32x4){c1, c1, c1, c1};
                gh1[g] = (f32x4){c2, c2, c2, c2};
            }
            #pragma unroll
            for (int ks = 0; ks < 7; ++ks) {
                short8 ax = *(const short8*)&s_x[arow][ks * 32 + kgrp * 8];
                short8 ad = *(const short8*)&s_db[arow][ks * 32 + kgrp * 8];
                #pragma unroll
                for (int g = 0; g < 3; ++g) {
                    gi0[g] = MFMA(ax, *(const short8*)&wp[P_WIH + ((size_t)(g*13 + t0)*7 + ks)*1024 + ln*8], gi0[g]);
                    gh0[g] = MFMA(ad, *(const short8*)&wp[P_WHH + ((size_t)(g*13 + t0)*7 + ks)*1024 + ln*8], gh0[g]);
                }
                if (has2) {
                    #pragma unroll
                    for (int g = 0; g < 3; ++g) {
                        gi1[g] = MFMA(ax, *(const short8*)&wp[P_WIH + ((size_t)(g*13 + t1)*7 + ks)*1024 + ln*8], gi1[g]);
                        gh1[g] = MFMA(ad, *(const short8*)&wp[P_WHH + ((size_t)(g*13 + t1)*7 + ks)*1024 + ln*8], gh1[g]);
                    }
                }
            }
            // in-register combine, tile 0
            if (j0 < 200) {
                #pragma unroll
                for (int e = 0; e < 4; ++e) {
                    int i = kgrp * 4 + e;
                    float rr = sig_f(gi0[0][e] + gh0[0][e]);
                    float zz = sig_f(gi0[1][e] + gh0[1][e]);
                    float nn = tanh_f(gi0[2][e] + rr * gh0[2][e]);
                    float d = (1.f - zz) * nn + zz * s_df[i][j0];
                    s_df[i][j0] = d;
                    s_db[i][j0] = f2b(d);
                    size_t o = ((size_t)(b0 + i) * NT + t) * OC;
                    out[o + 90 + j0]  = d;
                    out[o + 380 + j0] = d;
                }
            }
            if (has2 && j1 < 200) {   // tile 12, arow>=8 guarded
                #pragma unroll
                for (int e = 0; e < 4; ++e) {
                    int i = kgrp * 4 + e;
                    float rr = sig_f(gi1[0][e] + gh1[0][e]);
                    float zz = sig_f(gi1[1][e] + gh1[1][e]);
                    float nn = tanh_f(gi1[2][e] + rr * gh1[2][e]);
                    float d = (1.f - zz) * nn + zz * s_df[i][j1];
                    s_df[i][j1] = d;
                    s_db[i][j1] = f2b(d);
                    size_t o = ((size_t)(b0 + i) * NT + t) * OC;
                    out[o + 90 + j1]  = d;
                    out[o + 380 + j1] = d;
                }
            }
            // light waves: write staged data (loads drained here, in-phase)
            if (lightw && pN) {
                #pragma unroll
                for (int k = 0; k < 17; ++k) {
                    int idx = ll + k * 192;
                    if (idx < RB * 200) {
                        int i = idx / 200, j = idx - i * 200;
                        s_ep[p1][i][j] = epv[k];
                    }
                }
                if (ll < 96)
                    s_in0[ll / 6][30 + (ll % 6)] = f2b(av);
            }
        }
        bar_lds();

        // ---- phase C: hq = elu(deter_new @ Wq1a^T + Epre[p0]) ----
        float nz = 0.f;
        if (tid < RB * 30)
            nz = noise_post[((size_t)(b0 + tid / 30) * NT + t) * 30 + (tid % 30)];
        for (int tt = wv; tt < 13; tt += 8) {
            int j = tt * 16 + arow;
            f32x4 acc;
            #pragma unroll
            for (int e = 0; e < 4; ++e) acc[e] = s_ep[p0][kgrp * 4 + e][j];
            for (int ks = 0; ks < 7; ++ks) {
                short8 ad = *(const short8*)&s_db[arow][ks * 32 + kgrp * 8];
                short8 wf = *(const short8*)&wp[P_WQ1 + ((size_t)tt * 7 + ks) * 1024 + ln * 8];
                acc = MFMA(ad, wf, acc);
            }
            #pragma unroll
            for (int e = 0; e < 4; ++e)
                s_hq[kgrp * 4 + e][j] = f2b(elu_f(acc[e]));
        }
        bar_lds();

        // ---- phase D1: q = hq @ Wq2^T + bq2 (4 n-tiles on waves 0-3) ----
        if (wv < 4) {
            int tt = wv, j = tt * 16 + arow;
            float bv = s_bq2[j];
            f32x4 acc = {bv, bv, bv, bv};
            for (int ks = 0; ks < 7; ++ks) {
                short8 ah = *(const short8*)&s_hq[arow][ks * 32 + kgrp * 8];
                short8 wf = *(const short8*)&wp[P_WQ2 + ((size_t)tt * 7 + ks) * 1024 + ln * 8];
                acc = MFMA(ah, wf, acc);
            }
            #pragma unroll
            for (int e = 0; e < 4; ++e) s_q[kgrp * 4 + e][j] = acc[e];
        }
        bar_lds();

        // ---- phase D2: posterior sample + outputs + next stoch ----
        if (tid < RB * 30) {
            int i = tid / 30, s = tid % 30;
            float qm = s_q[i][s];
            float qs = sp_f(s_q[i][30 + s]) + 0.1f;
            size_t bt = (size_t)(b0 + i) * NT + t;
            float qst = nz * qs + qm;
            size_t o = bt * OC;
            out[o + s]      = qm;
            out[o + 30 + s] = qs;
            out[o + 60 + s] = qst;
            s_in0[i][s] = f2b(qst);
        }
        bar_lds();   // stoch visible before A(t+1)
    }
}

// ---------------------------------------------------------------------------
// Prior head (MFMA): 1024 blocks x 64 bt-rows, 256 thr (4 waves x 16 rows).
// ---------------------------------------------------------------------------
__global__ __launch_bounds__(256) void prior_mfma(
    const float* __restrict__ noise_prior, const u16* __restrict__ wp,
    const float* __restrict__ bp1, const float* __restrict__ bp2,
    float* __restrict__ out)
{
    __shared__ __align__(16) u16   s_hp[64][232];
    __shared__ __align__(16) float s_p[64][68];
    const int tid = threadIdx.x;
    const int wv = tid >> 6, ln = tid & 63;
    const int arow = ln & 15, kgrp = ln >> 4;
    const size_t bt0 = (size_t)blockIdx.x * 64;
    const int m0 = wv * 16;

    for (int idx = tid; idx < 64 * 32; idx += 256) {   // zero pad cols 200..231
        int r2 = idx >> 5, c = 200 + (idx & 31);
        s_hp[r2][c] = 0;
    }

    // GEMM1: hp = elu(deter @ Wp1^T + bp1)
    f32x4 acc[13];
    #pragma unroll
    for (int tt = 0; tt < 13; ++tt) {
        const int j = tt * 16 + arow;
        const float bv = (j < 200) ? bp1[j] : 0.f;
        acc[tt] = (f32x4){bv, bv, bv, bv};
    }
    for (int ks = 0; ks < 7; ++ks) {
        short8 a;
        const int k0 = ks * 32 + kgrp * 8;
        if (k0 <= 192) {
            const float* dp = &out[(bt0 + m0 + arow) * OC + 380 + k0];
            float4 v0 = *(const float4*)dp;
            float4 v1 = *(const float4*)(dp + 4);
            a = pack8(v0, v1);
        } else {
            a = (short8){0, 0, 0, 0, 0, 0, 0, 0};
        }
        const u16* bp = &wp[P_WP1 + (size_t)ks * 13 * 1024 + (size_t)ln * 8];
        #pragma unroll
        for (int tt = 0; tt < 13; ++tt)
            acc[tt] = MFMA(a, *(const short8*)(bp + (size_t)tt * 1024), acc[tt]);
    }
    #pragma unroll
    for (int tt = 0; tt < 13; ++tt)
        #pragma unroll
        for (int e = 0; e < 4; ++e)
            s_hp[m0 + kgrp * 4 + e][tt * 16 + arow] = f2b(elu_f(acc[tt][e]));
    __syncthreads();

    // GEMM2: p = hp @ Wp2^T + bp2
    f32x4 acc2[4];
    #pragma unroll
    for (int tt = 0; tt < 4; ++tt) {
        const int j = tt * 16 + arow;
        const float bv = (j < 60) ? bp2[j] : 0.f;
        acc2[tt] = (f32x4){bv, bv, bv, bv};
    }
    #pragma unroll
    for (int ks = 0; ks < 7; ++ks) {
        short8 ah = *(const short8*)&s_hp[m0 + arow][ks * 32 + kgrp * 8];
        const u16* bp = &wp[P_WP2 + (size_t)ks * 4 * 1024 + (size_t)ln * 8];
        #pragma unroll
        for (int tt = 0; tt < 4; ++tt)
            acc2[tt] = MFMA(ah, *(const short8*)(bp + (size_t)tt * 1024), acc2[tt]);
    }
    #pragma unroll
    for (int tt = 0; tt < 4; ++tt)
        #pragma unroll
        for (int e = 0; e < 4; ++e)
            s_p[m0 + kgrp * 4 + e][tt * 16 + arow] = acc2[tt][e];
    __syncthreads();

    for (int idx = tid; idx < 64 * 30; idx += 256) {
        int i = idx / 30, ss = idx - i * 30;
        float pm = s_p[i][ss];
        float ps = sp_f(s_p[i][30 + ss]) + 0.1f;
        float pst = noise_prior[(bt0 + i) * 30 + ss] * ps + pm;
        size_t base = (bt0 + i) * OC;
        out[base + 290 + ss] = pm;
        out[base + 320 + ss] = ps;
        out[base + 350 + ss] = pst;
    }
}

extern "C" void kernel_launch(void* const* d_in, const int* in_sizes, int n_in,
                              void* d_out, int out_size, void* d_ws, size_t ws_size,
                              hipStream_t stream)
{
    (void)in_sizes; (void)n_in; (void)out_size; (void)ws_size;
    const float* embed       = (const float*)d_in[0];
    const float* action      = (const float*)d_in[1];
    const float* noise_prior = (const float*)d_in[2];
    const float* noise_post  = (const float*)d_in[3];
    const float* Wi   = (const float*)d_in[4];
    const float* bi   = (const float*)d_in[5];
    const float* W_ih = (const float*)d_in[6];
    const float* W_hh = (const float*)d_in[7];
    const float* b_ih = (const float*)d_in[8];
    const float* b_hh = (const float*)d_in[9];
    const float* Wp1  = (const float*)d_in[10];
    const float* bp1  = (const float*)d_in[11];
    const float* Wp2  = (const float*)d_in[12];
    const float* bp2  = (const float*)d_in[13];
    const float* Wq1  = (const float*)d_in[14];
    const float* bq1  = (const float*)d_in[15];
    const float* Wq2  = (const float*)d_in[16];
    const float* bq2  = (const float*)d_in[17];
    float* out = (float*)d_out;
    u16* wp = (u16*)d_ws;

    hipLaunchKernelGGL(prep_pack, dim3((P_TOTAL + 255) / 256), dim3(256), 0, stream,
                       Wi, W_ih, W_hh, Wq1, Wq2, Wp1, Wp2, wp);
    hipLaunchKernelGGL(epre_mfma, dim3(256), dim3(512), 0, stream,
                       embed, wp, bq1, out);
    hipLaunchKernelGGL(scan_mfma, dim3(SCAN_BLOCKS), dim3(512), 0, stream,
                       action, noise_post, b_ih, b_hh, bi, bq2, wp, out);
    hipLaunchKernelGGL(prior_mfma, dim3(NBATCH * NT / 64), dim3(256), 0, stream,
                       noise_prior, wp, bp1, bp2, out);
}

// Round 16
// 1320.676 us; speedup vs baseline: 1.2965x; 1.2965x over previous
//
#include <hip/hip_runtime.h>
#include <math.h>

typedef unsigned short u16;
typedef unsigned int   u32;
typedef __attribute__((ext_vector_type(8))) short short8;
typedef __attribute__((ext_vector_type(4))) float f32x4;

#define NBATCH 1024
#define NT 64
#define OC 580
#define RB 16            // batch rows per scan block
#define SCAN_BLOCKS (NBATCH / RB)
#define SX 232           // bf16 LDS row stride
#define SF 212           // f32 LDS row stride

// packed bf16 weight fragments (1024-u16 spacing, 512 used) in d_ws (u16 units)
#define P_WI    0        // [tt13][ks2]
#define P_WIH   26624    // [(g*13+tt)][ks7]
#define P_WHH   306176
#define P_WQ1   585728   // [tt13][ks7]
#define P_WQ2   678912   // [tt4][ks7]
#define P_EB    707584   // [ks32][tt13]
#define P_WP1   1133568  // [ks7][tt13]
#define P_WP2   1226752  // [ks7][tt4]
#define P_TOTAL 1255424

__device__ __forceinline__ float elu_f(float x) { return x > 0.f ? x : __expf(x) - 1.f; }
__device__ __forceinline__ float sig_f(float x) { return __fdividef(1.f, 1.f + __expf(-x)); }
__device__ __forceinline__ float sp_f(float x)  { return x > 20.f ? x : log1pf(__expf(x)); }
__device__ __forceinline__ float tanh_f(float x) {   // fast tanh
    float ax = fabsf(x); ax = ax > 10.f ? 10.f : ax;
    float e = __expf(2.f * ax);
    float t = __fdividef(e - 1.f, e + 1.f);
    return copysignf(t, x);
}

// LDS-only barrier: no vmcnt(0) drain (scan has NO intra-kernel global RAW).
__device__ __forceinline__ void bar_lds() {
    __builtin_amdgcn_sched_barrier(0);
    asm volatile("s_waitcnt lgkmcnt(0)" ::: "memory");
    __builtin_amdgcn_s_barrier();
    __builtin_amdgcn_sched_barrier(0);
}

__device__ __forceinline__ u16 f2b(float f) {   // f32 -> bf16 RNE
    union { float f; u32 u; } v; v.f = f;
    u32 r = (v.u + 0x7fffu + ((v.u >> 16) & 1u)) >> 16;
    return (u16)r;
}

__device__ __forceinline__ short8 pack8(float4 v0, float4 v1) {
    short8 r;
    r[0] = (short)f2b(v0.x); r[1] = (short)f2b(v0.y);
    r[2] = (short)f2b(v0.z); r[3] = (short)f2b(v0.w);
    r[4] = (short)f2b(v1.x); r[5] = (short)f2b(v1.y);
    r[6] = (short)f2b(v1.z); r[7] = (short)f2b(v1.w);
    return r;
}

#define MFMA(a, b, c) __builtin_amdgcn_mfma_f32_16x16x32_bf16((a), (b), (c), 0, 0, 0)

// ---------------------------------------------------------------------------
// prep: pack weights to bf16 MFMA B-fragment order:
// frag[lane][e] = W[n0 + (lane&15)][k0 + (lane>>4)*8 + e]  (0-padded)
// ---------------------------------------------------------------------------
__global__ __launch_bounds__(256) void prep_pack(
    const float* __restrict__ Wi, const float* __restrict__ W_ih,
    const float* __restrict__ W_hh, const float* __restrict__ Wq1,
    const float* __restrict__ Wq2, const float* __restrict__ Wp1,
    const float* __restrict__ Wp2, u16* __restrict__ wp)
{
    for (size_t r = (size_t)blockIdx.x * 256 + threadIdx.x; r < P_TOTAL;
         r += (size_t)gridDim.x * 256) {
        float val = 0.f;
        if (r < P_WIH) {                           // Wi: [200 x 36]
            int tile = r / 1024, lane = (r % 1024) / 8, el = r % 8;
            int tt = tile / 2, ks = tile % 2;
            int j = tt * 16 + (lane & 15), k = ks * 32 + (lane >> 4) * 8 + el;
            if (j < 200 && k < 36 && lane < 64) val = Wi[j * 36 + k];
        } else if (r < P_WHH) {                    // W_ih
            size_t q = r - P_WIH;
            int tile = q / 1024, lane = (q % 1024) / 8, el = q % 8;
            int g = tile / 91, rem = tile % 91, tt = rem / 7, ks = rem % 7;
            int j = tt * 16 + (lane & 15), k = ks * 32 + (lane >> 4) * 8 + el;
            if (j < 200 && k < 200 && lane < 64) val = W_ih[(size_t)(g * 200 + j) * 200 + k];
        } else if (r < P_WQ1) {                    // W_hh
            size_t q = r - P_WHH;
            int tile = q / 1024, lane = (q % 1024) / 8, el = q % 8;
            int g = tile / 91, rem = tile % 91, tt = rem / 7, ks = rem % 7;
            int j = tt * 16 + (lane & 15), k = ks * 32 + (lane >> 4) * 8 + el;
            if (j < 200 && k < 200 && lane < 64) val = W_hh[(size_t)(g * 200 + j) * 200 + k];
        } else if (r < P_WQ2) {                    // Wq1[:, :200]
            size_t q = r - P_WQ1;
            int tile = q / 1024, lane = (q % 1024) / 8, el = q % 8;
            int tt = tile / 7, ks = tile % 7;
            int j = tt * 16 + (lane & 15), k = ks * 32 + (lane >> 4) * 8 + el;
            if (j < 200 && k < 200 && lane < 64) val = Wq1[(size_t)j * 1224 + k];
        } else if (r < P_EB) {                     // Wq2: [60 x 200]
            size_t q = r - P_WQ2;
            int tile = q / 1024, lane = (q % 1024) / 8, el = q % 8;
            int tt = tile / 7, ks = tile % 7;
            int j = tt * 16 + (lane & 15), k = ks * 32 + (lane >> 4) * 8 + el;
            if (j < 60 && k < 200 && lane < 64) val = Wq2[(size_t)j * 200 + k];
        } else if (r < P_WP1) {                    // epre B: Wq1[:,200:1224]
            size_t q = r - P_EB;
            int tile = q / 1024, lane = (q % 1024) / 8, el = q % 8;
            int ks = tile / 13, tt = tile % 13;
            int j = tt * 16 + (lane & 15), k = ks * 32 + (lane >> 4) * 8 + el;
            if (j < 200 && lane < 64) val = Wq1[(size_t)j * 1224 + 200 + k];
        } else if (r < P_WP2) {                    // Wp1: [200 x 200]
            size_t q = r - P_WP1;
            int tile = q / 1024, lane = (q % 1024) / 8, el = q % 8;
            int ks = tile / 13, tt = tile % 13;
            int j = tt * 16 + (lane & 15), k = ks * 32 + (lane >> 4) * 8 + el;
            if (j < 200 && k < 200 && lane < 64) val = Wp1[(size_t)j * 200 + k];
        } else {                                   // Wp2: [60 x 200]
            size_t q = r - P_WP2;
            int tile = q / 1024, lane = (q % 1024) / 8, el = q % 8;
            int ks = tile / 4, tt = tile % 4;
            int j = tt * 16 + (lane & 15), k = ks * 32 + (lane >> 4) * 8 + el;
            if (j < 60 && k < 200 && lane < 64) val = Wp2[(size_t)j * 200 + k];
        }
        wp[r] = f2b(val);
    }
}

// ---------------------------------------------------------------------------
// Epre (MFMA): out[bt*580+290+j] = embed[bt] . Wq1[j][200:] + bq1[j]
// ---------------------------------------------------------------------------
__global__ __launch_bounds__(512) void epre_mfma(
    const float* __restrict__ embed, const u16* __restrict__ wp,
    const float* __restrict__ bq1, float* __restrict__ out)
{
    const int tid = threadIdx.x;
    const int wv = tid >> 6, ln = tid & 63;
    const int arow = ln & 15, kgrp = ln >> 4;
    const int m0 = blockIdx.x * 256 + wv * 32;

    f32x4 acc[2][13];
    #pragma unroll
    for (int tt = 0; tt < 13; ++tt) {
        const int j = tt * 16 + arow;
        const float bv = (j < 200) ? bq1[j] : 0.f;
        acc[0][tt] = (f32x4){bv, bv, bv, bv};
        acc[1][tt] = acc[0][tt];
    }
    const float* e0 = &embed[(size_t)(m0 + arow) * 1024 + kgrp * 8];
    const float* e1 = e0 + (size_t)16 * 1024;

    for (int ks = 0; ks < 32; ++ks) {
        short8 a0, a1;
        {
            float4 v0 = *(const float4*)(e0 + ks * 32);
            float4 v1 = *(const float4*)(e0 + ks * 32 + 4);
            a0 = pack8(v0, v1);
            float4 w0 = *(const float4*)(e1 + ks * 32);
            float4 w1 = *(const float4*)(e1 + ks * 32 + 4);
            a1 = pack8(w0, w1);
        }
        const u16* bp = &wp[P_EB + (size_t)ks * 13 * 1024 + (size_t)ln * 8];
        #pragma unroll
        for (int tt = 0; tt < 13; ++tt) {
            short8 b = *(const short8*)(bp + (size_t)tt * 1024);
            acc[0][tt] = MFMA(a0, b, acc[0][tt]);
            acc[1][tt] = MFMA(a1, b, acc[1][tt]);
        }
    }
    #pragma unroll
    for (int f = 0; f < 2; ++f) {
        const size_t rbase = (size_t)(m0 + f * 16 + kgrp * 4);
        #pragma unroll
        for (int tt = 0; tt < 13; ++tt) {
            const int j = tt * 16 + arow;
            if (j < 200) {
                #pragma unroll
                for (int e = 0; e < 4; ++e)
                    out[(rbase + e) * OC + 290 + j] = acc[f][tt][e];
            }
        }
    }
}

// ---------------------------------------------------------------------------
// MFMA scan: 64 blocks x 16 batch rows, 512 threads (8 waves).
// r12 structure with the dedicated staging phase absorbed into phase C:
// double-buffered s_ep; Epre(t+1) loads issued at top of C, ds_written after
// C's MFMAs (same phase, no cross-barrier holds). action(t+1) prefetched in
// C (1 VGPR) and written in D2. 6 LDS-only barriers/step.
// ---------------------------------------------------------------------------
__global__ __launch_bounds__(512, 2) void scan_mfma(
    const float* __restrict__ action, const float* __restrict__ noise_post,
    const float* __restrict__ b_ih, const float* __restrict__ b_hh,
    const float* __restrict__ bi, const float* __restrict__ bq2,
    const u16* __restrict__ wp, float* __restrict__ out)
{
    __shared__ u16   s_in0[RB][72];           // [stoch30 | act6 | 0pad], K=64 used
    __shared__ u16   s_x[RB][SX];             // x bf16
    __shared__ u16   s_db[RB][SX];            // deter bf16 (MFMA shadow)
    __shared__ u16   s_hq[RB][SX];            // hq bf16
    __shared__ float s_df[RB][200];           // deter fp32 carry
    __shared__ float s_ep[2][RB][SF];         // Epre staged fp32 (double buffer)
    __shared__ float s_r[RB][SF], s_z[RB][SF], s_inn[RB][SF], s_hnn[RB][SF];
    __shared__ float s_q[RB][64];
    __shared__ float s_bih[3][208], s_bhh[3][208], s_bi[208], s_bq2[64];

    const int tid  = threadIdx.x;
    const int wv   = tid >> 6, ln = tid & 63;
    const int arow = ln & 15, kgrp = ln >> 4;
    const int b0   = blockIdx.x * RB;
    const int ia   = tid / 6, ca = tid - (tid / 6) * 6;   // action slot (tid<96)

    // init: zero bf16 activations (incl. K-pads) + s_ep + s_df, stage biases
    { u32* z = (u32*)s_in0; for (int i = tid; i < RB*72/2;  i += 512) z[i] = 0; }
    { u32* z = (u32*)s_x;   for (int i = tid; i < RB*SX/2;  i += 512) z[i] = 0; }
    { u32* z = (u32*)s_db;  for (int i = tid; i < RB*SX/2;  i += 512) z[i] = 0; }
    { u32* z = (u32*)s_hq;  for (int i = tid; i < RB*SX/2;  i += 512) z[i] = 0; }
    { float* z = (float*)s_ep; for (int i = tid; i < 2*RB*SF; i += 512) z[i] = 0.f; }
    { float* z = (float*)s_df; for (int i = tid; i < RB*200; i += 512) z[i] = 0.f; }
    for (int i = tid; i < 3 * 208; i += 512) {
        int g = i / 208, j = i % 208;
        s_bih[g][j] = j < 200 ? b_ih[g * 200 + j] : 0.f;
        s_bhh[g][j] = j < 200 ? b_hh[g * 200 + j] : 0.f;
    }
    for (int i = tid; i < 208; i += 512) s_bi[i] = i < 200 ? bi[i] : 0.f;
    if (tid < 64) s_bq2[tid] = tid < 60 ? bq2[tid] : 0.f;
    __syncthreads();   // init complete before prologue staging

    // ---- prologue: stage Epre(0) + action(0) ----
    for (int idx = tid; idx < RB * 200; idx += 512) {
        int i = idx / 200, j = idx - i * 200;
        s_ep[0][i][j] = out[((size_t)(b0 + i) * NT + 0) * OC + 290 + j];
    }
    if (tid < 96)
        s_in0[ia][30 + ca] = f2b(action[((size_t)(b0 + ia) * NT + 0) * 6 + ca]);
    __syncthreads();

    for (int t = 0; t < NT; ++t) {
        const int p0 = t & 1, p1 = (t + 1) & 1;
        const bool pN = (t + 1 < NT);

        // ---- phase A: x = elu([stoch|act] @ Wi^T + bi), 13 n-tiles ----
        for (int tt = wv; tt < 13; tt += 8) {
            float bv = s_bi[tt * 16 + arow];
            f32x4 acc = {bv, bv, bv, bv};
            #pragma unroll
            for (int ks = 0; ks < 2; ++ks) {
                short8 af = *(const short8*)&s_in0[arow][ks * 32 + kgrp * 8];
                short8 wf = *(const short8*)&wp[P_WI + (size_t)(tt * 2 + ks) * 1024 + ln * 8];
                acc = MFMA(af, wf, acc);
            }
            #pragma unroll
            for (int e = 0; e < 4; ++e)
                s_x[kgrp * 4 + e][tt * 16 + arow] = f2b(elu_f(acc[e]));
        }
        bar_lds();

        // ---- phase B: gi = x@W_ih^T, gh = deter@W_hh^T (5 units/wave) ----
        {
            f32x4 gi[5], gh[5];
            #pragma unroll
            for (int q = 0; q < 5; ++q) {
                int p = wv + 8 * q; int pe = p < 39 ? p : 0;
                int g = pe / 13, tt = pe % 13;
                float b1 = s_bih[g][tt * 16 + arow];
                float b2 = s_bhh[g][tt * 16 + arow];
                gi[q] = (f32x4){b1, b1, b1, b1};
                gh[q] = (f32x4){b2, b2, b2, b2};
            }
            #pragma unroll
            for (int ks = 0; ks < 7; ++ks) {
                short8 ax = *(const short8*)&s_x[arow][ks * 32 + kgrp * 8];
                short8 ad = *(const short8*)&s_db[arow][ks * 32 + kgrp * 8];
                #pragma unroll
                for (int q = 0; q < 5; ++q) {
                    int p = wv + 8 * q; int pe = p < 39 ? p : 0;
                    short8 w1 = *(const short8*)&wp[P_WIH + ((size_t)pe * 7 + ks) * 1024 + ln * 8];
                    short8 w2 = *(const short8*)&wp[P_WHH + ((size_t)pe * 7 + ks) * 1024 + ln * 8];
                    gi[q] = MFMA(ax, w1, gi[q]);
                    gh[q] = MFMA(ad, w2, gh[q]);
                }
            }
            #pragma unroll
            for (int q = 0; q < 5; ++q) {
                int p = wv + 8 * q;
                if (p < 39) {
                    int g = p / 13, tt = p % 13, j = tt * 16 + arow;
                    #pragma unroll
                    for (int e = 0; e < 4; ++e) {
                        int i = kgrp * 4 + e;
                        if (g == 0)      s_r[i][j] = sig_f(gi[q][e] + gh[q][e]);
                        else if (g == 1) s_z[i][j] = sig_f(gi[q][e] + gh[q][e]);
                        else { s_inn[i][j] = gi[q][e]; s_hnn[i][j] = gh[q][e]; }
                    }
                }
            }
        }
        bar_lds();

        // ---- GRU combine: deter_new = (1-z)*tanh(inn + r*hnn) + z*deter ----
        for (int idx = tid; idx < RB * 200; idx += 512) {
            int i = idx / 200, j = idx % 200;
            float rr = s_r[i][j], zz = s_z[i][j];
            float nn = tanh_f(s_inn[i][j] + rr * s_hnn[i][j]);
            float d = (1.f - zz) * nn + zz * s_df[i][j];
            s_df[i][j] = d;
            s_db[i][j] = f2b(d);
            size_t o = ((size_t)(b0 + i) * NT + t) * OC;
            out[o + 90 + j]  = d;   // post deter
            out[o + 380 + j] = d;   // prior deter
        }
        bar_lds();

        // ---- phase C: Epre(t+1) staging (issue-early/write-late, in-phase)
        //      + hq = elu(deter_new @ Wq1a^T + Epre[p0]) ----
        float nz = 0.f, actp = 0.f;
        if (tid < RB * 30)
            nz = noise_post[((size_t)(b0 + tid / 30) * NT + t) * 30 + (tid % 30)];
        if (pN && tid < 96)
            actp = action[((size_t)(b0 + ia) * NT + (t + 1)) * 6 + ca];
        float epp[7];
        if (pN) {
            #pragma unroll
            for (int q = 0; q < 7; ++q) {
                int idx = tid + q * 512;
                if (idx < RB * 200) {
                    int i = idx / 200, j = idx - i * 200;
                    epp[q] = out[((size_t)(b0 + i) * NT + (t + 1)) * OC + 290 + j];
                }
            }
        }
        for (int tt = wv; tt < 13; tt += 8) {
            int j = tt * 16 + arow;
            f32x4 acc;
            #pragma unroll
            for (int e = 0; e < 4; ++e) acc[e] = s_ep[p0][kgrp * 4 + e][j];
            for (int ks = 0; ks < 7; ++ks) {
                short8 ad = *(const short8*)&s_db[arow][ks * 32 + kgrp * 8];
                short8 wf = *(const short8*)&wp[P_WQ1 + ((size_t)tt * 7 + ks) * 1024 + ln * 8];
                acc = MFMA(ad, wf, acc);
            }
            #pragma unroll
            for (int e = 0; e < 4; ++e)
                s_hq[kgrp * 4 + e][j] = f2b(elu_f(acc[e]));
        }
        if (pN) {   // staged loads drained here, still inside phase C
            #pragma unroll
            for (int q = 0; q < 7; ++q) {
                int idx = tid + q * 512;
                if (idx < RB * 200) {
                    int i = idx / 200, j = idx - i * 200;
                    s_ep[p1][i][j] = epp[q];
                }
            }
        }
        bar_lds();

        // ---- phase D1: q = hq @ Wq2^T + bq2 (4 n-tiles on waves 0-3) ----
        if (wv < 4) {
            int tt = wv, j = tt * 16 + arow;
            float bv = s_bq2[j];
            f32x4 acc = {bv, bv, bv, bv};
            for (int ks = 0; ks < 7; ++ks) {
                short8 ah = *(const short8*)&s_hq[arow][ks * 32 + kgrp * 8];
                short8 wf = *(const short8*)&wp[P_WQ2 + ((size_t)tt * 7 + ks) * 1024 + ln * 8];
                acc = MFMA(ah, wf, acc);
            }
            #pragma unroll
            for (int e = 0; e < 4; ++e) s_q[kgrp * 4 + e][j] = acc[e];
        }
        bar_lds();

        // ---- phase D2: posterior sample + outputs + next stoch + action ----
        if (tid < RB * 30) {
            int i = tid / 30, s = tid % 30;
            float qm = s_q[i][s];
            float qs = sp_f(s_q[i][30 + s]) + 0.1f;
            size_t bt = (size_t)(b0 + i) * NT + t;
            float qst = nz * qs + qm;
            size_t o = bt * OC;
            out[o + s]      = qm;
            out[o + 30 + s] = qs;
            out[o + 60 + s] = qst;
            s_in0[i][s] = f2b(qst);
        }
        if (pN && tid < 96)
            s_in0[ia][30 + ca] = f2b(actp);
        bar_lds();   // stoch/action visible before A(t+1)
    }
}

// ---------------------------------------------------------------------------
// Prior head (MFMA): 1024 blocks x 64 bt-rows, 256 thr (4 waves x 16 rows).
// ---------------------------------------------------------------------------
__global__ __launch_bounds__(256) void prior_mfma(
    const float* __restrict__ noise_prior, const u16* __restrict__ wp,
    const float* __restrict__ bp1, const float* __restrict__ bp2,
    float* __restrict__ out)
{
    __shared__ __align__(16) u16   s_hp[64][232];
    __shared__ __align__(16) float s_p[64][68];
    const int tid = threadIdx.x;
    const int wv = tid >> 6, ln = tid & 63;
    const int arow = ln & 15, kgrp = ln >> 4;
    const size_t bt0 = (size_t)blockIdx.x * 64;
    const int m0 = wv * 16;

    for (int idx = tid; idx < 64 * 32; idx += 256) {   // zero pad cols 200..231
        int r2 = idx >> 5, c = 200 + (idx & 31);
        s_hp[r2][c] = 0;
    }

    // GEMM1: hp = elu(deter @ Wp1^T + bp1)
    f32x4 acc[13];
    #pragma unroll
    for (int tt = 0; tt < 13; ++tt) {
        const int j = tt * 16 + arow;
        const float bv = (j < 200) ? bp1[j] : 0.f;
        acc[tt] = (f32x4){bv, bv, bv, bv};
    }
    for (int ks = 0; ks < 7; ++ks) {
        short8 a;
        const int k0 = ks * 32 + kgrp * 8;
        if (k0 <= 192) {
            const float* dp = &out[(bt0 + m0 + arow) * OC + 380 + k0];
            float4 v0 = *(const float4*)dp;
            float4 v1 = *(const float4*)(dp + 4);
            a = pack8(v0, v1);
        } else {
            a = (short8){0, 0, 0, 0, 0, 0, 0, 0};
        }
        const u16* bp = &wp[P_WP1 + (size_t)ks * 13 * 1024 + (size_t)ln * 8];
        #pragma unroll
        for (int tt = 0; tt < 13; ++tt)
            acc[tt] = MFMA(a, *(const short8*)(bp + (size_t)tt * 1024), acc[tt]);
    }
    #pragma unroll
    for (int tt = 0; tt < 13; ++tt)
        #pragma unroll
        for (int e = 0; e < 4; ++e)
            s_hp[m0 + kgrp * 4 + e][tt * 16 + arow] = f2b(elu_f(acc[tt][e]));
    __syncthreads();

    // GEMM2: p = hp @ Wp2^T + bp2
    f32x4 acc2[4];
    #pragma unroll
    for (int tt = 0; tt < 4; ++tt) {
        const int j = tt * 16 + arow;
        const float bv = (j < 60) ? bp2[j] : 0.f;
        acc2[tt] = (f32x4){bv, bv, bv, bv};
    }
    #pragma unroll
    for (int ks = 0; ks < 7; ++ks) {
        short8 ah = *(const short8*)&s_hp[m0 + arow][ks * 32 + kgrp * 8];
        const u16* bp = &wp[P_WP2 + (size_t)ks * 4 * 1024 + (size_t)ln * 8];
        #pragma unroll
        for (int tt = 0; tt < 4; ++tt)
            acc2[tt] = MFMA(ah, *(const short8*)(bp + (size_t)tt * 1024), acc2[tt]);
    }
    #pragma unroll
    for (int tt = 0; tt < 4; ++tt)
        #pragma unroll
        for (int e = 0; e < 4; ++e)
            s_p[m0 + kgrp * 4 + e][tt * 16 + arow] = acc2[tt][e];
    __syncthreads();

    for (int idx = tid; idx < 64 * 30; idx += 256) {
        int i = idx / 30, ss = idx - i * 30;
        float pm = s_p[i][ss];
        float ps = sp_f(s_p[i][30 + ss]) + 0.1f;
        float pst = noise_prior[(bt0 + i) * 30 + ss] * ps + pm;
        size_t base = (bt0 + i) * OC;
        out[base + 290 + ss] = pm;
        out[base + 320 + ss] = ps;
        out[base + 350 + ss] = pst;
    }
}

extern "C" void kernel_launch(void* const* d_in, const int* in_sizes, int n_in,
                              void* d_out, int out_size, void* d_ws, size_t ws_size,
                              hipStream_t stream)
{
    (void)in_sizes; (void)n_in; (void)out_size; (void)ws_size;
    const float* embed       = (const float*)d_in[0];
    const float* action      = (const float*)d_in[1];
    const float* noise_prior = (const float*)d_in[2];
    const float* noise_post  = (const float*)d_in[3];
    const float* Wi   = (const float*)d_in[4];
    const float* bi   = (const float*)d_in[5];
    const float* W_ih = (const float*)d_in[6];
    const float* W_hh = (const float*)d_in[7];
    const float* b_ih = (const float*)d_in[8];
    const float* b_hh = (const float*)d_in[9];
    const float* Wp1  = (const float*)d_in[10];
    const float* bp1  = (const float*)d_in[11];
    const float* Wp2  = (const float*)d_in[12];
    const float* bp2  = (const float*)d_in[13];
    const float* Wq1  = (const float*)d_in[14];
    const float* bq1  = (const float*)d_in[15];
    const float* Wq2  = (const float*)d_in[16];
    const float* bq2  = (const float*)d_in[17];
    float* out = (float*)d_out;
    u16* wp = (u16*)d_ws;

    hipLaunchKernelGGL(prep_pack, dim3((P_TOTAL + 255) / 256), dim3(256), 0, stream,
                       Wi, W_ih, W_hh, Wq1, Wq2, Wp1, Wp2, wp);
    hipLaunchKernelGGL(epre_mfma, dim3(256), dim3(512), 0, stream,
                       embed, wp, bq1, out);
    hipLaunchKernelGGL(scan_mfma, dim3(SCAN_BLOCKS), dim3(512), 0, stream,
                       action, noise_post, b_ih, b_hh, bi, bq2, wp, out);
    hipLaunchKernelGGL(prior_mfma, dim3(NBATCH * NT / 64), dim3(256), 0, stream,
                       noise_prior, wp, bp1, bp2, out);
}

// Round 17
// 1238.964 us; speedup vs baseline: 1.3820x; 1.0660x over previous
//
#include <hip/hip_runtime.h>
#include <math.h>

typedef unsigned short u16;
typedef unsigned int   u32;
typedef __attribute__((ext_vector_type(8))) short short8;
typedef __attribute__((ext_vector_type(4))) float f32x4;

#define NBATCH 1024
#define NT 64
#define OC 580
#define RB 16            // batch rows per scan block
#define SCAN_BLOCKS (NBATCH / RB)
#define SX 232           // bf16 LDS row stride
#define SF 212           // f32 LDS row stride

// packed bf16 weight fragments (1024-u16 spacing, 512 used) in d_ws (u16 units)
#define P_WI    0        // [tt13][ks2]
#define P_WIH   26624    // [(g*13+tt)][ks7]
#define P_WHH   306176
#define P_WQ1   585728   // [tt13][ks7]
#define P_WQ2   678912   // [tt4][ks7]
#define P_EB    707584   // [ks32][tt13]
#define P_WP1   1133568  // [ks7][tt13]
#define P_WP2   1226752  // [ks7][tt4]
#define P_TOTAL 1255424

__device__ __forceinline__ float elu_f(float x) { return x > 0.f ? x : __expf(x) - 1.f; }
__device__ __forceinline__ float sig_f(float x) { return __fdividef(1.f, 1.f + __expf(-x)); }
__device__ __forceinline__ float sp_f(float x)  { return x > 20.f ? x : log1pf(__expf(x)); }
__device__ __forceinline__ float tanh_f(float x) {   // fast tanh
    float ax = fabsf(x); ax = ax > 10.f ? 10.f : ax;
    float e = __expf(2.f * ax);
    float t = __fdividef(e - 1.f, e + 1.f);
    return copysignf(t, x);
}

// LDS-only barrier: no vmcnt(0) drain (scan has NO intra-kernel global RAW;
// global stores may complete lazily). lgkmcnt(0) orders LDS producer->barrier;
// sched_barrier(0) pins the scheduler on both sides (rule #18).
__device__ __forceinline__ void bar_lds() {
    __builtin_amdgcn_sched_barrier(0);
    asm volatile("s_waitcnt lgkmcnt(0)" ::: "memory");
    __builtin_amdgcn_s_barrier();
    __builtin_amdgcn_sched_barrier(0);
}

__device__ __forceinline__ u16 f2b(float f) {   // f32 -> bf16 RNE
    union { float f; u32 u; } v; v.f = f;
    u32 r = (v.u + 0x7fffu + ((v.u >> 16) & 1u)) >> 16;
    return (u16)r;
}

__device__ __forceinline__ short8 pack8(float4 v0, float4 v1) {
    short8 r;
    r[0] = (short)f2b(v0.x); r[1] = (short)f2b(v0.y);
    r[2] = (short)f2b(v0.z); r[3] = (short)f2b(v0.w);
    r[4] = (short)f2b(v1.x); r[5] = (short)f2b(v1.y);
    r[6] = (short)f2b(v1.z); r[7] = (short)f2b(v1.w);
    return r;
}

#define MFMA(a, b, c) __builtin_amdgcn_mfma_f32_16x16x32_bf16((a), (b), (c), 0, 0, 0)

// ---------------------------------------------------------------------------
// prep: pack weights to bf16 MFMA B-fragment order:
// frag[lane][e] = W[n0 + (lane&15)][k0 + (lane>>4)*8 + e]  (0-padded)
// ---------------------------------------------------------------------------
__global__ __launch_bounds__(256) void prep_pack(
    const float* __restrict__ Wi, const float* __restrict__ W_ih,
    const float* __restrict__ W_hh, const float* __restrict__ Wq1,
    const float* __restrict__ Wq2, const float* __restrict__ Wp1,
    const float* __restrict__ Wp2, u16* __restrict__ wp)
{
    for (size_t r = (size_t)blockIdx.x * 256 + threadIdx.x; r < P_TOTAL;
         r += (size_t)gridDim.x * 256) {
        float val = 0.f;
        if (r < P_WIH) {                           // Wi: [200 x 36]
            int tile = r / 1024, lane = (r % 1024) / 8, el = r % 8;
            int tt = tile / 2, ks = tile % 2;
            int j = tt * 16 + (lane & 15), k = ks * 32 + (lane >> 4) * 8 + el;
            if (j < 200 && k < 36 && lane < 64) val = Wi[j * 36 + k];
        } else if (r < P_WHH) {                    // W_ih
            size_t q = r - P_WIH;
            int tile = q / 1024, lane = (q % 1024) / 8, el = q % 8;
            int g = tile / 91, rem = tile % 91, tt = rem / 7, ks = rem % 7;
            int j = tt * 16 + (lane & 15), k = ks * 32 + (lane >> 4) * 8 + el;
            if (j < 200 && k < 200 && lane < 64) val = W_ih[(size_t)(g * 200 + j) * 200 + k];
        } else if (r < P_WQ1) {                    // W_hh
            size_t q = r - P_WHH;
            int tile = q / 1024, lane = (q % 1024) / 8, el = q % 8;
            int g = tile / 91, rem = tile % 91, tt = rem / 7, ks = rem % 7;
            int j = tt * 16 + (lane & 15), k = ks * 32 + (lane >> 4) * 8 + el;
            if (j < 200 && k < 200 && lane < 64) val = W_hh[(size_t)(g * 200 + j) * 200 + k];
        } else if (r < P_WQ2) {                    // Wq1[:, :200]
            size_t q = r - P_WQ1;
            int tile = q / 1024, lane = (q % 1024) / 8, el = q % 8;
            int tt = tile / 7, ks = tile % 7;
            int j = tt * 16 + (lane & 15), k = ks * 32 + (lane >> 4) * 8 + el;
            if (j < 200 && k < 200 && lane < 64) val = Wq1[(size_t)j * 1224 + k];
        } else if (r < P_EB) {                     // Wq2: [60 x 200]
            size_t q = r - P_WQ2;
            int tile = q / 1024, lane = (q % 1024) / 8, el = q % 8;
            int tt = tile / 7, ks = tile % 7;
            int j = tt * 16 + (lane & 15), k = ks * 32 + (lane >> 4) * 8 + el;
            if (j < 60 && k < 200 && lane < 64) val = Wq2[(size_t)j * 200 + k];
        } else if (r < P_WP1) {                    // epre B: Wq1[:,200:1224]
            size_t q = r - P_EB;
            int tile = q / 1024, lane = (q % 1024) / 8, el = q % 8;
            int ks = tile / 13, tt = tile % 13;
            int j = tt * 16 + (lane & 15), k = ks * 32 + (lane >> 4) * 8 + el;
            if (j < 200 && lane < 64) val = Wq1[(size_t)j * 1224 + 200 + k];
        } else if (r < P_WP2) {                    // Wp1: [200 x 200]
            size_t q = r - P_WP1;
            int tile = q / 1024, lane = (q % 1024) / 8, el = q % 8;
            int ks = tile / 13, tt = tile % 13;
            int j = tt * 16 + (lane & 15), k = ks * 32 + (lane >> 4) * 8 + el;
            if (j < 200 && k < 200 && lane < 64) val = Wp1[(size_t)j * 200 + k];
        } else {                                   // Wp2: [60 x 200]
            size_t q = r - P_WP2;
            int tile = q / 1024, lane = (q % 1024) / 8, el = q % 8;
            int ks = tile / 4, tt = tile % 4;
            int j = tt * 16 + (lane & 15), k = ks * 32 + (lane >> 4) * 8 + el;
            if (j < 60 && k < 200 && lane < 64) val = Wp2[(size_t)j * 200 + k];
        }
        wp[r] = f2b(val);
    }
}

// ---------------------------------------------------------------------------
// Epre (MFMA): out[bt*580+290+j] = embed[bt] . Wq1[j][200:] + bq1[j]
// ---------------------------------------------------------------------------
__global__ __launch_bounds__(512) void epre_mfma(
    const float* __restrict__ embed, const u16* __restrict__ wp,
    const float* __restrict__ bq1, float* __restrict__ out)
{
    const int tid = threadIdx.x;
    const int wv = tid >> 6, ln = tid & 63;
    const int arow = ln & 15, kgrp = ln >> 4;
    const int m0 = blockIdx.x * 256 + wv * 32;

    f32x4 acc[2][13];
    #pragma unroll
    for (int tt = 0; tt < 13; ++tt) {
        const int j = tt * 16 + arow;
        const float bv = (j < 200) ? bq1[j] : 0.f;
        acc[0][tt] = (f32x4){bv, bv, bv, bv};
        acc[1][tt] = acc[0][tt];
    }
    const float* e0 = &embed[(size_t)(m0 + arow) * 1024 + kgrp * 8];
    const float* e1 = e0 + (size_t)16 * 1024;

    for (int ks = 0; ks < 32; ++ks) {
        short8 a0, a1;
        {
            float4 v0 = *(const float4*)(e0 + ks * 32);
            float4 v1 = *(const float4*)(e0 + ks * 32 + 4);
            a0 = pack8(v0, v1);
            float4 w0 = *(const float4*)(e1 + ks * 32);
            float4 w1 = *(const float4*)(e1 + ks * 32 + 4);
            a1 = pack8(w0, w1);
        }
        const u16* bp = &wp[P_EB + (size_t)ks * 13 * 1024 + (size_t)ln * 8];
        #pragma unroll
        for (int tt = 0; tt < 13; ++tt) {
            short8 b = *(const short8*)(bp + (size_t)tt * 1024);
            acc[0][tt] = MFMA(a0, b, acc[0][tt]);
            acc[1][tt] = MFMA(a1, b, acc[1][tt]);
        }
    }
    #pragma unroll
    for (int f = 0; f < 2; ++f) {
        const size_t rbase = (size_t)(m0 + f * 16 + kgrp * 4);
        #pragma unroll
        for (int tt = 0; tt < 13; ++tt) {
            const int j = tt * 16 + arow;
            if (j < 200) {
                #pragma unroll
                for (int e = 0; e < 4; ++e)
                    out[(rbase + e) * OC + 290 + j] = acc[f][tt][e];
            }
        }
    }
}

// ---------------------------------------------------------------------------
// MFMA scan: 64 blocks x 16 batch rows, 512 threads (8 waves).
// r9 base (persistent W_hh, inline W_ih, dedicated staging phase) +
// LDS-only barriers in the t-loop (no vmcnt drain) + fast tanh +
// noise_post prefetch (1 VGPR, issued in phase C).  [r12 verbatim — best]
// ---------------------------------------------------------------------------
__global__ __launch_bounds__(512, 2) void scan_mfma(
    const float* __restrict__ action, const float* __restrict__ noise_post,
    const float* __restrict__ b_ih, const float* __restrict__ b_hh,
    const float* __restrict__ bi, const float* __restrict__ bq2,
    const u16* __restrict__ wp, float* __restrict__ out)
{
    __shared__ u16   s_in0[RB][72];           // [stoch30 | act6 | 0pad], K=64 used
    __shared__ u16   s_x[RB][SX];             // x bf16
    __shared__ u16   s_db[RB][SX];            // deter bf16 (MFMA shadow)
    __shared__ u16   s_hq[RB][SX];            // hq bf16
    __shared__ float s_df[RB][200];           // deter fp32 carry
    __shared__ float s_ep[RB][SF];            // Epre staged fp32
    __shared__ float s_r[RB][SF], s_z[RB][SF], s_inn[RB][SF], s_hnn[RB][SF];
    __shared__ float s_q[RB][64];
    __shared__ float s_bih[3][208], s_bhh[3][208], s_bi[208], s_bq2[64];

    const int tid  = threadIdx.x;
    const int wv   = tid >> 6, ln = tid & 63;
    const int arow = ln & 15, kgrp = ln >> 4;
    const int b0   = blockIdx.x * RB;

    // init: zero bf16 activations (incl. K-pads) + s_ep + s_df, stage biases
    { u32* z = (u32*)s_in0; for (int i = tid; i < RB*72/2;  i += 512) z[i] = 0; }
    { u32* z = (u32*)s_x;   for (int i = tid; i < RB*SX/2;  i += 512) z[i] = 0; }
    { u32* z = (u32*)s_db;  for (int i = tid; i < RB*SX/2;  i += 512) z[i] = 0; }
    { u32* z = (u32*)s_hq;  for (int i = tid; i < RB*SX/2;  i += 512) z[i] = 0; }
    { float* z = (float*)s_ep; for (int i = tid; i < RB*SF; i += 512) z[i] = 0.f; }
    { float* z = (float*)s_df; for (int i = tid; i < RB*200; i += 512) z[i] = 0.f; }
    for (int i = tid; i < 3 * 208; i += 512) {
        int g = i / 208, j = i % 208;
        s_bih[g][j] = j < 200 ? b_ih[g * 200 + j] : 0.f;
        s_bhh[g][j] = j < 200 ? b_hh[g * 200 + j] : 0.f;
    }
    for (int i = tid; i < 208; i += 512) s_bi[i] = i < 200 ? bi[i] : 0.f;
    if (tid < 64) s_bq2[tid] = tid < 60 ? bq2[tid] : 0.f;

    // ---- persistent W_hh fragments: 5 units x 7 ks, hoisted out of t-loop ----
    short8 whhP[5][7];
    #pragma unroll
    for (int q = 0; q < 5; ++q) {
        int p = wv + 8 * q; int pe = p < 39 ? p : 0;
        #pragma unroll
        for (int ks = 0; ks < 7; ++ks)
            whhP[q][ks] = *(const short8*)&wp[P_WHH + ((size_t)pe * 7 + ks) * 1024 + ln * 8];
    }
    __syncthreads();   // full barrier once before the loop

    for (int t = 0; t < NT; ++t) {
        // ---- stage Epre (16x200, written by epre_mfma) + action(t) ----
        for (int idx = tid; idx < RB * 200; idx += 512) {
            int i = idx / 200, j = idx % 200;
            s_ep[i][j] = out[((size_t)(b0 + i) * NT + t) * OC + 290 + j];
        }
        if (tid < RB * 6) {
            int i = tid / 6, c = tid % 6;
            s_in0[i][30 + c] = f2b(action[((size_t)(b0 + i) * NT + t) * 6 + c]);
        }
        bar_lds();

        // ---- phase A: x = elu([stoch|act] @ Wi^T + bi), 13 n-tiles ----
        for (int tt = wv; tt < 13; tt += 8) {
            float bv = s_bi[tt * 16 + arow];
            f32x4 acc = {bv, bv, bv, bv};
            #pragma unroll
            for (int ks = 0; ks < 2; ++ks) {
                short8 af = *(const short8*)&s_in0[arow][ks * 32 + kgrp * 8];
                short8 wf = *(const short8*)&wp[P_WI + (size_t)(tt * 2 + ks) * 1024 + ln * 8];
                acc = MFMA(af, wf, acc);
            }
            #pragma unroll
            for (int e = 0; e < 4; ++e)
                s_x[kgrp * 4 + e][tt * 16 + arow] = f2b(elu_f(acc[e]));
        }
        bar_lds();

        // ---- phase B: gi = x@W_ih^T (inline), gh = deter@W_hh^T (registers) ----
        {
            f32x4 gi[5], gh[5];
            #pragma unroll
            for (int q = 0; q < 5; ++q) {
                int p = wv + 8 * q; int pe = p < 39 ? p : 0;
                int g = pe / 13, tt = pe % 13;
                float b1 = s_bih[g][tt * 16 + arow];
                float b2 = s_bhh[g][tt * 16 + arow];
                gi[q] = (f32x4){b1, b1, b1, b1};
                gh[q] = (f32x4){b2, b2, b2, b2};
            }
            #pragma unroll
            for (int ks = 0; ks < 7; ++ks) {
                short8 ax = *(const short8*)&s_x[arow][ks * 32 + kgrp * 8];
                short8 ad = *(const short8*)&s_db[arow][ks * 32 + kgrp * 8];
                #pragma unroll
                for (int q = 0; q < 5; ++q) {
                    int p = wv + 8 * q; int pe = p < 39 ? p : 0;
                    short8 w1 = *(const short8*)&wp[P_WIH + ((size_t)pe * 7 + ks) * 1024 + ln * 8];
                    gi[q] = MFMA(ax, w1, gi[q]);
                    gh[q] = MFMA(ad, whhP[q][ks], gh[q]);
                }
            }
            #pragma unroll
            for (int q = 0; q < 5; ++q) {
                int p = wv + 8 * q;
                if (p < 39) {
                    int g = p / 13, tt = p % 13, j = tt * 16 + arow;
                    #pragma unroll
                    for (int e = 0; e < 4; ++e) {
                        int i = kgrp * 4 + e;
                        if (g == 0)      s_r[i][j] = sig_f(gi[q][e] + gh[q][e]);
                        else if (g == 1) s_z[i][j] = sig_f(gi[q][e] + gh[q][e]);
                        else { s_inn[i][j] = gi[q][e]; s_hnn[i][j] = gh[q][e]; }
                    }
                }
            }
        }
        bar_lds();

        // ---- GRU combine: deter_new = (1-z)*tanh(inn + r*hnn) + z*deter ----
        for (int idx = tid; idx < RB * 200; idx += 512) {
            int i = idx / 200, j = idx % 200;
            float rr = s_r[i][j], zz = s_z[i][j];
            float nn = tanh_f(s_inn[i][j] + rr * s_hnn[i][j]);
            float d = (1.f - zz) * nn + zz * s_df[i][j];
            s_df[i][j] = d;
            s_db[i][j] = f2b(d);
            size_t o = ((size_t)(b0 + i) * NT + t) * OC;
            out[o + 90 + j]  = d;   // post deter
            out[o + 380 + j] = d;   // prior deter
        }
        bar_lds();

        // ---- phase C: hq = elu(deter_new @ Wq1a^T + Epre) ----
        // noise_post prefetch (1 VGPR, consumed in D2 two barriers later)
        float nz = 0.f;
        if (tid < RB * 30)
            nz = noise_post[((size_t)(b0 + tid / 30) * NT + t) * 30 + (tid % 30)];
        for (int tt = wv; tt < 13; tt += 8) {
            int j = tt * 16 + arow;
            f32x4 acc;
            #pragma unroll
            for (int e = 0; e < 4; ++e) acc[e] = s_ep[kgrp * 4 + e][j];
            for (int ks = 0; ks < 7; ++ks) {
                short8 ad = *(const short8*)&s_db[arow][ks * 32 + kgrp * 8];
                short8 wf = *(const short8*)&wp[P_WQ1 + ((size_t)tt * 7 + ks) * 1024 + ln * 8];
                acc = MFMA(ad, wf, acc);
            }
            #pragma unroll
            for (int e = 0; e < 4; ++e)
                s_hq[kgrp * 4 + e][j] = f2b(elu_f(acc[e]));
        }
        bar_lds();

        // ---- phase D1: q = hq @ Wq2^T + bq2 (4 n-tiles on waves 0-3) ----
        if (wv < 4) {
            int tt = wv, j = tt * 16 + arow;
            float bv = s_bq2[j];
            f32x4 acc = {bv, bv, bv, bv};
            for (int ks = 0; ks < 7; ++ks) {
                short8 ah = *(const short8*)&s_hq[arow][ks * 32 + kgrp * 8];
                short8 wf = *(const short8*)&wp[P_WQ2 + ((size_t)tt * 7 + ks) * 1024 + ln * 8];
                acc = MFMA(ah, wf, acc);
            }
            #pragma unroll
            for (int e = 0; e < 4; ++e) s_q[kgrp * 4 + e][j] = acc[e];
        }
        bar_lds();

        // ---- phase D2: posterior sample + outputs + next stoch ----
        if (tid < RB * 30) {
            int i = tid / 30, s = tid % 30;
            float qm = s_q[i][s];
            float qs = sp_f(s_q[i][30 + s]) + 0.1f;
            size_t bt = (size_t)(b0 + i) * NT + t;
            float qst = nz * qs + qm;
            size_t o = bt * OC;
            out[o + s]      = qm;
            out[o + 30 + s] = qs;
            out[o + 60 + s] = qst;
            s_in0[i][s] = f2b(qst);
        }
        // no barrier: next staging phase writes disjoint LDS; bar_lds follows it
    }
}

// ---------------------------------------------------------------------------
// Prior head (MFMA): 1024 blocks x 64 bt-rows, 256 thr (4 waves x 16 rows).
// ---------------------------------------------------------------------------
__global__ __launch_bounds__(256) void prior_mfma(
    const float* __restrict__ noise_prior, const u16* __restrict__ wp,
    const float* __restrict__ bp1, const float* __restrict__ bp2,
    float* __restrict__ out)
{
    __shared__ __align__(16) u16   s_hp[64][232];
    __shared__ __align__(16) float s_p[64][68];
    const int tid = threadIdx.x;
    const int wv = tid >> 6, ln = tid & 63;
    const int arow = ln & 15, kgrp = ln >> 4;
    const size_t bt0 = (size_t)blockIdx.x * 64;
    const int m0 = wv * 16;

    for (int idx = tid; idx < 64 * 32; idx += 256) {   // zero pad cols 200..231
        int r2 = idx >> 5, c = 200 + (idx & 31);
        s_hp[r2][c] = 0;
    }

    // GEMM1: hp = elu(deter @ Wp1^T + bp1)
    f32x4 acc[13];
    #pragma unroll
    for (int tt = 0; tt < 13; ++tt) {
        const int j = tt * 16 + arow;
        const float bv = (j < 200) ? bp1[j] : 0.f;
        acc[tt] = (f32x4){bv, bv, bv, bv};
    }
    for (int ks = 0; ks < 7; ++ks) {
        short8 a;
        const int k0 = ks * 32 + kgrp * 8;
        if (k0 <= 192) {
            const float* dp = &out[(bt0 + m0 + arow) * OC + 380 + k0];
            float4 v0 = *(const float4*)dp;
            float4 v1 = *(const float4*)(dp + 4);
            a = pack8(v0, v1);
        } else {
            a = (short8){0, 0, 0, 0, 0, 0, 0, 0};
        }
        const u16* bp = &wp[P_WP1 + (size_t)ks * 13 * 1024 + (size_t)ln * 8];
        #pragma unroll
        for (int tt = 0; tt < 13; ++tt)
            acc[tt] = MFMA(a, *(const short8*)(bp + (size_t)tt * 1024), acc[tt]);
    }
    #pragma unroll
    for (int tt = 0; tt < 13; ++tt)
        #pragma unroll
        for (int e = 0; e < 4; ++e)
            s_hp[m0 + kgrp * 4 + e][tt * 16 + arow] = f2b(elu_f(acc[tt][e]));
    __syncthreads();

    // GEMM2: p = hp @ Wp2^T + bp2
    f32x4 acc2[4];
    #pragma unroll
    for (int tt = 0; tt < 4; ++tt) {
        const int j = tt * 16 + arow;
        const float bv = (j < 60) ? bp2[j] : 0.f;
        acc2[tt] = (f32x4){bv, bv, bv, bv};
    }
    #pragma unroll
    for (int ks = 0; ks < 7; ++ks) {
        short8 ah = *(const short8*)&s_hp[m0 + arow][ks * 32 + kgrp * 8];
        const u16* bp = &wp[P_WP2 + (size_t)ks * 4 * 1024 + (size_t)ln * 8];
        #pragma unroll
        for (int tt = 0; tt < 4; ++tt)
            acc2[tt] = MFMA(ah, *(const short8*)(bp + (size_t)tt * 1024), acc2[tt]);
    }
    #pragma unroll
    for (int tt = 0; tt < 4; ++tt)
        #pragma unroll
        for (int e = 0; e < 4; ++e)
            s_p[m0 + kgrp * 4 + e][tt * 16 + arow] = acc2[tt][e];
    __syncthreads();

    for (int idx = tid; idx < 64 * 30; idx += 256) {
        int i = idx / 30, ss = idx - i * 30;
        float pm = s_p[i][ss];
        float ps = sp_f(s_p[i][30 + ss]) + 0.1f;
        float pst = noise_prior[(bt0 + i) * 30 + ss] * ps + pm;
        size_t base = (bt0 + i) * OC;
        out[base + 290 + ss] = pm;
        out[base + 320 + ss] = ps;
        out[base + 350 + ss] = pst;
    }
}

extern "C" void kernel_launch(void* const* d_in, const int* in_sizes, int n_in,
                              void* d_out, int out_size, void* d_ws, size_t ws_size,
                              hipStream_t stream)
{
    (void)in_sizes; (void)n_in; (void)out_size; (void)ws_size;
    const float* embed       = (const float*)d_in[0];
    const float* action      = (const float*)d_in[1];
    const float* noise_prior = (const float*)d_in[2];
    const float* noise_post  = (const float*)d_in[3];
    const float* Wi   = (const float*)d_in[4];
    const float* bi   = (const float*)d_in[5];
    const float* W_ih = (const float*)d_in[6];
    const float* W_hh = (const float*)d_in[7];
    const float* b_ih = (const float*)d_in[8];
    const float* b_hh = (const float*)d_in[9];
    const float* Wp1  = (const float*)d_in[10];
    const float* bp1  = (const float*)d_in[11];
    const float* Wp2  = (const float*)d_in[12];
    const float* bp2  = (const float*)d_in[13];
    const float* Wq1  = (const float*)d_in[14];
    const float* bq1  = (const float*)d_in[15];
    const float* Wq2  = (const float*)d_in[16];
    const float* bq2  = (const float*)d_in[17];
    float* out = (float*)d_out;
    u16* wp = (u16*)d_ws;

    hipLaunchKernelGGL(prep_pack, dim3((P_TOTAL + 255) / 256), dim3(256), 0, stream,
                       Wi, W_ih, W_hh, Wq1, Wq2, Wp1, Wp2, wp);
    hipLaunchKernelGGL(epre_mfma, dim3(256), dim3(512), 0, stream,
                       embed, wp, bq1, out);
    hipLaunchKernelGGL(scan_mfma, dim3(SCAN_BLOCKS), dim3(512), 0, stream,
                       action, noise_post, b_ih, b_hh, bi, bq2, wp, out);
    hipLaunchKernelGGL(prior_mfma, dim3(NBATCH * NT / 64), dim3(256), 0, stream,
                       noise_prior, wp, bp1, bp2, out);
}

// Round 18
// 1185.846 us; speedup vs baseline: 1.4439x; 1.0448x over previous
//
#include <hip/hip_runtime.h>
#include <math.h>

typedef unsigned short u16;
typedef unsigned int   u32;
typedef __attribute__((ext_vector_type(8))) short short8;
typedef __attribute__((ext_vector_type(4))) float f32x4;

#define NBATCH 1024
#define NT 64
#define OC 580
#define RB 8             // batch rows per scan block (half-tile; 2 blocks/CU)
#define SCAN_BLOCKS (NBATCH / RB)
#define SX 232           // bf16 LDS row stride
#define SF 212           // f32 LDS row stride

// packed bf16 weight fragments (1024-u16 spacing, 512 used) in d_ws (u16 units)
#define P_WI    0        // [tt13][ks2]
#define P_WIH   26624    // [(g*13+tt)][ks7]
#define P_WHH   306176
#define P_WQ1   585728   // [tt13][ks7]
#define P_WQ2   678912   // [tt4][ks7]
#define P_EB    707584   // [ks32][tt13]
#define P_WP1   1133568  // [ks7][tt13]
#define P_WP2   1226752  // [ks7][tt4]
#define P_TOTAL 1255424

__device__ __forceinline__ float elu_f(float x) { return x > 0.f ? x : __expf(x) - 1.f; }
__device__ __forceinline__ float sig_f(float x) { return __fdividef(1.f, 1.f + __expf(-x)); }
__device__ __forceinline__ float sp_f(float x)  { return x > 20.f ? x : log1pf(__expf(x)); }
__device__ __forceinline__ float tanh_f(float x) {   // fast tanh
    float ax = fabsf(x); ax = ax > 10.f ? 10.f : ax;
    float e = __expf(2.f * ax);
    float t = __fdividef(e - 1.f, e + 1.f);
    return copysignf(t, x);
}

// LDS-only barrier: no vmcnt(0) drain (scan has NO intra-kernel global RAW).
__device__ __forceinline__ void bar_lds() {
    __builtin_amdgcn_sched_barrier(0);
    asm volatile("s_waitcnt lgkmcnt(0)" ::: "memory");
    __builtin_amdgcn_s_barrier();
    __builtin_amdgcn_sched_barrier(0);
}

__device__ __forceinline__ u16 f2b(float f) {   // f32 -> bf16 RNE
    union { float f; u32 u; } v; v.f = f;
    u32 r = (v.u + 0x7fffu + ((v.u >> 16) & 1u)) >> 16;
    return (u16)r;
}

__device__ __forceinline__ short8 pack8(float4 v0, float4 v1) {
    short8 r;
    r[0] = (short)f2b(v0.x); r[1] = (short)f2b(v0.y);
    r[2] = (short)f2b(v0.z); r[3] = (short)f2b(v0.w);
    r[4] = (short)f2b(v1.x); r[5] = (short)f2b(v1.y);
    r[6] = (short)f2b(v1.z); r[7] = (short)f2b(v1.w);
    return r;
}

#define MFMA(a, b, c) __builtin_amdgcn_mfma_f32_16x16x32_bf16((a), (b), (c), 0, 0, 0)

// ---------------------------------------------------------------------------
// prep: pack weights to bf16 MFMA B-fragment order:
// frag[lane][e] = W[n0 + (lane&15)][k0 + (lane>>4)*8 + e]  (0-padded)
// ---------------------------------------------------------------------------
__global__ __launch_bounds__(256) void prep_pack(
    const float* __restrict__ Wi, const float* __restrict__ W_ih,
    const float* __restrict__ W_hh, const float* __restrict__ Wq1,
    const float* __restrict__ Wq2, const float* __restrict__ Wp1,
    const float* __restrict__ Wp2, u16* __restrict__ wp)
{
    for (size_t r = (size_t)blockIdx.x * 256 + threadIdx.x; r < P_TOTAL;
         r += (size_t)gridDim.x * 256) {
        float val = 0.f;
        if (r < P_WIH) {                           // Wi: [200 x 36]
            int tile = r / 1024, lane = (r % 1024) / 8, el = r % 8;
            int tt = tile / 2, ks = tile % 2;
            int j = tt * 16 + (lane & 15), k = ks * 32 + (lane >> 4) * 8 + el;
            if (j < 200 && k < 36 && lane < 64) val = Wi[j * 36 + k];
        } else if (r < P_WHH) {                    // W_ih
            size_t q = r - P_WIH;
            int tile = q / 1024, lane = (q % 1024) / 8, el = q % 8;
            int g = tile / 91, rem = tile % 91, tt = rem / 7, ks = rem % 7;
            int j = tt * 16 + (lane & 15), k = ks * 32 + (lane >> 4) * 8 + el;
            if (j < 200 && k < 200 && lane < 64) val = W_ih[(size_t)(g * 200 + j) * 200 + k];
        } else if (r < P_WQ1) {                    // W_hh
            size_t q = r - P_WHH;
            int tile = q / 1024, lane = (q % 1024) / 8, el = q % 8;
            int g = tile / 91, rem = tile % 91, tt = rem / 7, ks = rem % 7;
            int j = tt * 16 + (lane & 15), k = ks * 32 + (lane >> 4) * 8 + el;
            if (j < 200 && k < 200 && lane < 64) val = W_hh[(size_t)(g * 200 + j) * 200 + k];
        } else if (r < P_WQ2) {                    // Wq1[:, :200]
            size_t q = r - P_WQ1;
            int tile = q / 1024, lane = (q % 1024) / 8, el = q % 8;
            int tt = tile / 7, ks = tile % 7;
            int j = tt * 16 + (lane & 15), k = ks * 32 + (lane >> 4) * 8 + el;
            if (j < 200 && k < 200 && lane < 64) val = Wq1[(size_t)j * 1224 + k];
        } else if (r < P_EB) {                     // Wq2: [60 x 200]
            size_t q = r - P_WQ2;
            int tile = q / 1024, lane = (q % 1024) / 8, el = q % 8;
            int tt = tile / 7, ks = tile % 7;
            int j = tt * 16 + (lane & 15), k = ks * 32 + (lane >> 4) * 8 + el;
            if (j < 60 && k < 200 && lane < 64) val = Wq2[(size_t)j * 200 + k];
        } else if (r < P_WP1) {                    // epre B: Wq1[:,200:1224]
            size_t q = r - P_EB;
            int tile = q / 1024, lane = (q % 1024) / 8, el = q % 8;
            int ks = tile / 13, tt = tile % 13;
            int j = tt * 16 + (lane & 15), k = ks * 32 + (lane >> 4) * 8 + el;
            if (j < 200 && lane < 64) val = Wq1[(size_t)j * 1224 + 200 + k];
        } else if (r < P_WP2) {                    // Wp1: [200 x 200]
            size_t q = r - P_WP1;
            int tile = q / 1024, lane = (q % 1024) / 8, el = q % 8;
            int ks = tile / 13, tt = tile % 13;
            int j = tt * 16 + (lane & 15), k = ks * 32 + (lane >> 4) * 8 + el;
            if (j < 200 && k < 200 && lane < 64) val = Wp1[(size_t)j * 200 + k];
        } else {                                   // Wp2: [60 x 200]
            size_t q = r - P_WP2;
            int tile = q / 1024, lane = (q % 1024) / 8, el = q % 8;
            int ks = tile / 4, tt = tile % 4;
            int j = tt * 16 + (lane & 15), k = ks * 32 + (lane >> 4) * 8 + el;
            if (j < 60 && k < 200 && lane < 64) val = Wp2[(size_t)j * 200 + k];
        }
        wp[r] = f2b(val);
    }
}

// ---------------------------------------------------------------------------
// Epre (MFMA): out[bt*580+290+j] = embed[bt] . Wq1[j][200:] + bq1[j]
// ---------------------------------------------------------------------------
__global__ __launch_bounds__(512) void epre_mfma(
    const float* __restrict__ embed, const u16* __restrict__ wp,
    const float* __restrict__ bq1, float* __restrict__ out)
{
    const int tid = threadIdx.x;
    const int wv = tid >> 6, ln = tid & 63;
    const int arow = ln & 15, kgrp = ln >> 4;
    const int m0 = blockIdx.x * 256 + wv * 32;

    f32x4 acc[2][13];
    #pragma unroll
    for (int tt = 0; tt < 13; ++tt) {
        const int j = tt * 16 + arow;
        const float bv = (j < 200) ? bq1[j] : 0.f;
        acc[0][tt] = (f32x4){bv, bv, bv, bv};
        acc[1][tt] = acc[0][tt];
    }
    const float* e0 = &embed[(size_t)(m0 + arow) * 1024 + kgrp * 8];
    const float* e1 = e0 + (size_t)16 * 1024;

    for (int ks = 0; ks < 32; ++ks) {
        short8 a0, a1;
        {
            float4 v0 = *(const float4*)(e0 + ks * 32);
            float4 v1 = *(const float4*)(e0 + ks * 32 + 4);
            a0 = pack8(v0, v1);
            float4 w0 = *(const float4*)(e1 + ks * 32);
            float4 w1 = *(const float4*)(e1 + ks * 32 + 4);
            a1 = pack8(w0, w1);
        }
        const u16* bp = &wp[P_EB + (size_t)ks * 13 * 1024 + (size_t)ln * 8];
        #pragma unroll
        for (int tt = 0; tt < 13; ++tt) {
            short8 b = *(const short8*)(bp + (size_t)tt * 1024);
            acc[0][tt] = MFMA(a0, b, acc[0][tt]);
            acc[1][tt] = MFMA(a1, b, acc[1][tt]);
        }
    }
    #pragma unroll
    for (int f = 0; f < 2; ++f) {
        const size_t rbase = (size_t)(m0 + f * 16 + kgrp * 4);
        #pragma unroll
        for (int tt = 0; tt < 13; ++tt) {
            const int j = tt * 16 + arow;
            if (j < 200) {
                #pragma unroll
                for (int e = 0; e < 4; ++e)
                    out[(rbase + e) * OC + 290 + j] = acc[f][tt][e];
            }
        }
    }
}

// ---------------------------------------------------------------------------
// MFMA scan: 128 blocks x 8 batch rows, 512 threads (8 waves), 2 blocks/CU.
// r12 schedule verbatim; M=16 MFMA tiles half-padded (rows 8-15 garbage,
// row-confined, never stored). f32 arrays 8 rows; bf16 A-arrays 16 rows
// (rows 8-15 zero or garbage, harmless).
// ---------------------------------------------------------------------------
__global__ __launch_bounds__(512, 2) void scan_mfma(
    const float* __restrict__ action, const float* __restrict__ noise_post,
    const float* __restrict__ b_ih, const float* __restrict__ b_hh,
    const float* __restrict__ bi, const float* __restrict__ bq2,
    const u16* __restrict__ wp, float* __restrict__ out)
{
    __shared__ u16   s_in0[16][72];           // [stoch30 | act6 | 0pad]
    __shared__ u16   s_x[16][SX];             // x bf16
    __shared__ u16   s_db[16][SX];            // deter bf16 (MFMA shadow)
    __shared__ u16   s_hq[16][SX];            // hq bf16
    __shared__ float s_df[RB][200];           // deter fp32 carry
    __shared__ float s_ep[RB][SF];            // Epre staged fp32
    __shared__ float s_r[RB][SF], s_z[RB][SF], s_inn[RB][SF], s_hnn[RB][SF];
    __shared__ float s_q[16][64];
    __shared__ float s_bih[3][208], s_bhh[3][208], s_bi[208], s_bq2[64];

    const int tid  = threadIdx.x;
    const int wv   = tid >> 6, ln = tid & 63;
    const int arow = ln & 15, kgrp = ln >> 4;
    const int b0   = blockIdx.x * RB;

    // init: zero bf16 activations (incl. pad rows 8-15) + s_ep + s_df, biases
    { u32* z = (u32*)s_in0; for (int i = tid; i < 16*72/2;  i += 512) z[i] = 0; }
    { u32* z = (u32*)s_x;   for (int i = tid; i < 16*SX/2;  i += 512) z[i] = 0; }
    { u32* z = (u32*)s_db;  for (int i = tid; i < 16*SX/2;  i += 512) z[i] = 0; }
    { u32* z = (u32*)s_hq;  for (int i = tid; i < 16*SX/2;  i += 512) z[i] = 0; }
    { float* z = (float*)s_ep; for (int i = tid; i < RB*SF; i += 512) z[i] = 0.f; }
    { float* z = (float*)s_df; for (int i = tid; i < RB*200; i += 512) z[i] = 0.f; }
    for (int i = tid; i < 3 * 208; i += 512) {
        int g = i / 208, j = i % 208;
        s_bih[g][j] = j < 200 ? b_ih[g * 200 + j] : 0.f;
        s_bhh[g][j] = j < 200 ? b_hh[g * 200 + j] : 0.f;
    }
    for (int i = tid; i < 208; i += 512) s_bi[i] = i < 200 ? bi[i] : 0.f;
    if (tid < 64) s_bq2[tid] = tid < 60 ? bq2[tid] : 0.f;

    // ---- persistent W_hh fragments: 5 units x 7 ks ----
    short8 whhP[5][7];
    #pragma unroll
    for (int q = 0; q < 5; ++q) {
        int p = wv + 8 * q; int pe = p < 39 ? p : 0;
        #pragma unroll
        for (int ks = 0; ks < 7; ++ks)
            whhP[q][ks] = *(const short8*)&wp[P_WHH + ((size_t)pe * 7 + ks) * 1024 + ln * 8];
    }
    __syncthreads();   // full barrier once before the loop

    for (int t = 0; t < NT; ++t) {
        // ---- stage Epre (8x200) + action(t) ----
        for (int idx = tid; idx < RB * 200; idx += 512) {
            int i = idx / 200, j = idx % 200;
            s_ep[i][j] = out[((size_t)(b0 + i) * NT + t) * OC + 290 + j];
        }
        if (tid < RB * 6) {
            int i = tid / 6, c = tid % 6;
            s_in0[i][30 + c] = f2b(action[((size_t)(b0 + i) * NT + t) * 6 + c]);
        }
        bar_lds();

        // ---- phase A: x = elu([stoch|act] @ Wi^T + bi), 13 n-tiles ----
        for (int tt = wv; tt < 13; tt += 8) {
            float bv = s_bi[tt * 16 + arow];
            f32x4 acc = {bv, bv, bv, bv};
            #pragma unroll
            for (int ks = 0; ks < 2; ++ks) {
                short8 af = *(const short8*)&s_in0[arow][ks * 32 + kgrp * 8];
                short8 wf = *(const short8*)&wp[P_WI + (size_t)(tt * 2 + ks) * 1024 + ln * 8];
                acc = MFMA(af, wf, acc);
            }
            #pragma unroll
            for (int e = 0; e < 4; ++e)
                s_x[kgrp * 4 + e][tt * 16 + arow] = f2b(elu_f(acc[e]));
        }
        bar_lds();

        // ---- phase B: gi = x@W_ih^T (inline), gh = deter@W_hh^T (regs) ----
        {
            f32x4 gi[5], gh[5];
            #pragma unroll
            for (int q = 0; q < 5; ++q) {
                int p = wv + 8 * q; int pe = p < 39 ? p : 0;
                int g = pe / 13, tt = pe % 13;
                float b1 = s_bih[g][tt * 16 + arow];
                float b2 = s_bhh[g][tt * 16 + arow];
                gi[q] = (f32x4){b1, b1, b1, b1};
                gh[q] = (f32x4){b2, b2, b2, b2};
            }
            #pragma unroll
            for (int ks = 0; ks < 7; ++ks) {
                short8 ax = *(const short8*)&s_x[arow][ks * 32 + kgrp * 8];
                short8 ad = *(const short8*)&s_db[arow][ks * 32 + kgrp * 8];
                #pragma unroll
                for (int q = 0; q < 5; ++q) {
                    int p = wv + 8 * q; int pe = p < 39 ? p : 0;
                    short8 w1 = *(const short8*)&wp[P_WIH + ((size_t)pe * 7 + ks) * 1024 + ln * 8];
                    gi[q] = MFMA(ax, w1, gi[q]);
                    gh[q] = MFMA(ad, whhP[q][ks], gh[q]);
                }
            }
            if (kgrp < 2) {   // rows 0..7 only (f32 gate arrays are [8])
                #pragma unroll
                for (int q = 0; q < 5; ++q) {
                    int p = wv + 8 * q;
                    if (p < 39) {
                        int g = p / 13, tt = p % 13, j = tt * 16 + arow;
                        #pragma unroll
                        for (int e = 0; e < 4; ++e) {
                            int i = kgrp * 4 + e;
                            if (g == 0)      s_r[i][j] = sig_f(gi[q][e] + gh[q][e]);
                            else if (g == 1) s_z[i][j] = sig_f(gi[q][e] + gh[q][e]);
                            else { s_inn[i][j] = gi[q][e]; s_hnn[i][j] = gh[q][e]; }
                        }
                    }
                }
            }
        }
        bar_lds();

        // ---- GRU combine: deter_new = (1-z)*tanh(inn + r*hnn) + z*deter ----
        for (int idx = tid; idx < RB * 200; idx += 512) {
            int i = idx / 200, j = idx % 200;
            float rr = s_r[i][j], zz = s_z[i][j];
            float nn = tanh_f(s_inn[i][j] + rr * s_hnn[i][j]);
            float d = (1.f - zz) * nn + zz * s_df[i][j];
            s_df[i][j] = d;
            s_db[i][j] = f2b(d);
            size_t o = ((size_t)(b0 + i) * NT + t) * OC;
            out[o + 90 + j]  = d;   // post deter
            out[o + 380 + j] = d;   // prior deter
        }
        bar_lds();

        // ---- phase C: hq = elu(deter_new @ Wq1a^T + Epre) ----
        float nz = 0.f;
        if (tid < RB * 30)
            nz = noise_post[((size_t)(b0 + tid / 30) * NT + t) * 30 + (tid % 30)];
        for (int tt = wv; tt < 13; tt += 8) {
            int j = tt * 16 + arow;
            f32x4 acc;
            #pragma unroll
            for (int e = 0; e < 4; ++e)
                acc[e] = s_ep[(kgrp * 4 + e) & 7][j];   // rows 8-15: dup, discarded
            for (int ks = 0; ks < 7; ++ks) {
                short8 ad = *(const short8*)&s_db[arow][ks * 32 + kgrp * 8];
                short8 wf = *(const short8*)&wp[P_WQ1 + ((size_t)tt * 7 + ks) * 1024 + ln * 8];
                acc = MFMA(ad, wf, acc);
            }
            #pragma unroll
            for (int e = 0; e < 4; ++e)
                s_hq[kgrp * 4 + e][j] = f2b(elu_f(acc[e]));
        }
        bar_lds();

        // ---- phase D1: q = hq @ Wq2^T + bq2 (4 n-tiles on waves 0-3) ----
        if (wv < 4) {
            int tt = wv, j = tt * 16 + arow;
            float bv = s_bq2[j];
            f32x4 acc = {bv, bv, bv, bv};
            for (int ks = 0; ks < 7; ++ks) {
                short8 ah = *(const short8*)&s_hq[arow][ks * 32 + kgrp * 8];
                short8 wf = *(const short8*)&wp[P_WQ2 + ((size_t)tt * 7 + ks) * 1024 + ln * 8];
                acc = MFMA(ah, wf, acc);
            }
            #pragma unroll
            for (int e = 0; e < 4; ++e) s_q[kgrp * 4 + e][j] = acc[e];
        }
        bar_lds();

        // ---- phase D2: posterior sample + outputs + next stoch ----
        if (tid < RB * 30) {
            int i = tid / 30, s = tid % 30;
            float qm = s_q[i][s];
            float qs = sp_f(s_q[i][30 + s]) + 0.1f;
            size_t bt = (size_t)(b0 + i) * NT + t;
            float qst = nz * qs + qm;
            size_t o = bt * OC;
            out[o + s]      = qm;
            out[o + 30 + s] = qs;
            out[o + 60 + s] = qst;
            s_in0[i][s] = f2b(qst);
        }
        // no barrier: next staging phase writes disjoint LDS; bar_lds follows it
    }
}

// ---------------------------------------------------------------------------
// Prior head (MFMA): 1024 blocks x 64 bt-rows, 256 thr (4 waves x 16 rows).
// ---------------------------------------------------------------------------
__global__ __launch_bounds__(256) void prior_mfma(
    const float* __restrict__ noise_prior, const u16* __restrict__ wp,
    const float* __restrict__ bp1, const float* __restrict__ bp2,
    float* __restrict__ out)
{
    __shared__ __align__(16) u16   s_hp[64][232];
    __shared__ __align__(16) float s_p[64][68];
    const int tid = threadIdx.x;
    const int wv = tid >> 6, ln = tid & 63;
    const int arow = ln & 15, kgrp = ln >> 4;
    const size_t bt0 = (size_t)blockIdx.x * 64;
    const int m0 = wv * 16;

    for (int idx = tid; idx < 64 * 32; idx += 256) {   // zero pad cols 200..231
        int r2 = idx >> 5, c = 200 + (idx & 31);
        s_hp[r2][c] = 0;
    }

    // GEMM1: hp = elu(deter @ Wp1^T + bp1)
    f32x4 acc[13];
    #pragma unroll
    for (int tt = 0; tt < 13; ++tt) {
        const int j = tt * 16 + arow;
        const float bv = (j < 200) ? bp1[j] : 0.f;
        acc[tt] = (f32x4){bv, bv, bv, bv};
    }
    for (int ks = 0; ks < 7; ++ks) {
        short8 a;
        const int k0 = ks * 32 + kgrp * 8;
        if (k0 <= 192) {
            const float* dp = &out[(bt0 + m0 + arow) * OC + 380 + k0];
            float4 v0 = *(const float4*)dp;
            float4 v1 = *(const float4*)(dp + 4);
            a = pack8(v0, v1);
        } else {
            a = (short8){0, 0, 0, 0, 0, 0, 0, 0};
        }
        const u16* bp = &wp[P_WP1 + (size_t)ks * 13 * 1024 + (size_t)ln * 8];
        #pragma unroll
        for (int tt = 0; tt < 13; ++tt)
            acc[tt] = MFMA(a, *(const short8*)(bp + (size_t)tt * 1024), acc[tt]);
    }
    #pragma unroll
    for (int tt = 0; tt < 13; ++tt)
        #pragma unroll
        for (int e = 0; e < 4; ++e)
            s_hp[m0 + kgrp * 4 + e][tt * 16 + arow] = f2b(elu_f(acc[tt][e]));
    __syncthreads();

    // GEMM2: p = hp @ Wp2^T + bp2
    f32x4 acc2[4];
    #pragma unroll
    for (int tt = 0; tt < 4; ++tt) {
        const int j = tt * 16 + arow;
        const float bv = (j < 60) ? bp2[j] : 0.f;
        acc2[tt] = (f32x4){bv, bv, bv, bv};
    }
    #pragma unroll
    for (int ks = 0; ks < 7; ++ks) {
        short8 ah = *(const short8*)&s_hp[m0 + arow][ks * 32 + kgrp * 8];
        const u16* bp = &wp[P_WP2 + (size_t)ks * 4 * 1024 + (size_t)ln * 8];
        #pragma unroll
        for (int tt = 0; tt < 4; ++tt)
            acc2[tt] = MFMA(ah, *(const short8*)(bp + (size_t)tt * 1024), acc2[tt]);
    }
    #pragma unroll
    for (int tt = 0; tt < 4; ++tt)
        #pragma unroll
        for (int e = 0; e < 4; ++e)
            s_p[m0 + kgrp * 4 + e][tt * 16 + arow] = acc2[tt][e];
    __syncthreads();

    for (int idx = tid; idx < 64 * 30; idx += 256) {
        int i = idx / 30, ss = idx - i * 30;
        float pm = s_p[i][ss];
        float ps = sp_f(s_p[i][30 + ss]) + 0.1f;
        float pst = noise_prior[(bt0 + i) * 30 + ss] * ps + pm;
        size_t base = (bt0 + i) * OC;
        out[base + 290 + ss] = pm;
        out[base + 320 + ss] = ps;
        out[base + 350 + ss] = pst;
    }
}

extern "C" void kernel_launch(void* const* d_in, const int* in_sizes, int n_in,
                              void* d_out, int out_size, void* d_ws, size_t ws_size,
                              hipStream_t stream)
{
    (void)in_sizes; (void)n_in; (void)out_size; (void)ws_size;
    const float* embed       = (const float*)d_in[0];
    const float* action      = (const float*)d_in[1];
    const float* noise_prior = (const float*)d_in[2];
    const float* noise_post  = (const float*)d_in[3];
    const float* Wi   = (const float*)d_in[4];
    const float* bi   = (const float*)d_in[5];
    const float* W_ih = (const float*)d_in[6];
    const float* W_hh = (const float*)d_in[7];
    const float* b_ih = (const float*)d_in[8];
    const float* b_hh = (const float*)d_in[9];
    const float* Wp1  = (const float*)d_in[10];
    const float* bp1  = (const float*)d_in[11];
    const float* Wp2  = (const float*)d_in[12];
    const float* bp2  = (const float*)d_in[13];
    const float* Wq1  = (const float*)d_in[14];
    const float* bq1  = (const float*)d_in[15];
    const float* Wq2  = (const float*)d_in[16];
    const float* bq2  = (const float*)d_in[17];
    float* out = (float*)d_out;
    u16* wp = (u16*)d_ws;

    hipLaunchKernelGGL(prep_pack, dim3((P_TOTAL + 255) / 256), dim3(256), 0, stream,
                       Wi, W_ih, W_hh, Wq1, Wq2, Wp1, Wp2, wp);
    hipLaunchKernelGGL(epre_mfma, dim3(256), dim3(512), 0, stream,
                       embed, wp, bq1, out);
    hipLaunchKernelGGL(scan_mfma, dim3(SCAN_BLOCKS), dim3(512), 0, stream,
                       action, noise_post, b_ih, b_hh, bi, bq2, wp, out);
    hipLaunchKernelGGL(prior_mfma, dim3(NBATCH * NT / 64), dim3(256), 0, stream,
                       noise_prior, wp, bp1, bp2, out);
}

// Round 20
// 1149.070 us; speedup vs baseline: 1.4901x; 1.0320x over previous
//
#include <hip/hip_runtime.h>
#include <math.h>

typedef unsigned short u16;
typedef unsigned int   u32;
typedef __attribute__((ext_vector_type(8))) short short8;
typedef __attribute__((ext_vector_type(4))) float f32x4;

#define NBATCH 1024
#define NT 64
#define OC 580
#define RB 8             // batch rows per scan block (half-tile; 2 blocks/CU)
#define SCAN_BLOCKS (NBATCH / RB)
#define SX 232           // bf16 LDS row stride
#define SF 212           // f32 LDS row stride

// packed bf16 weight fragments (1024-u16 spacing, 512 used) in d_ws (u16 units)
#define P_WI    0        // [tt13][ks2]
#define P_WIH   26624    // [(g*13+tt)][ks7]
#define P_WHH   306176
#define P_WQ1   585728   // [tt13][ks7]
#define P_WQ2   678912   // [tt4][ks7]
#define P_EB    707584   // [ks32][tt13]
#define P_WP1   1133568  // [ks7][tt13]
#define P_WP2   1226752  // [ks7][tt4]
#define P_TOTAL 1255424

__device__ __forceinline__ float elu_f(float x) { return x > 0.f ? x : __expf(x) - 1.f; }
__device__ __forceinline__ float sig_f(float x) { return __fdividef(1.f, 1.f + __expf(-x)); }
__device__ __forceinline__ float sp_f(float x)  { return x > 20.f ? x : log1pf(__expf(x)); }
__device__ __forceinline__ float tanh_f(float x) {   // fast tanh
    float ax = fabsf(x); ax = ax > 10.f ? 10.f : ax;
    float e = __expf(2.f * ax);
    float t = __fdividef(e - 1.f, e + 1.f);
    return copysignf(t, x);
}

// LDS-only barrier: no vmcnt(0) drain (scan has NO intra-kernel global RAW
// within a step once ordering below is respected).
__device__ __forceinline__ void bar_lds() {
    __builtin_amdgcn_sched_barrier(0);
    asm volatile("s_waitcnt lgkmcnt(0)" ::: "memory");
    __builtin_amdgcn_s_barrier();
    __builtin_amdgcn_sched_barrier(0);
}

__device__ __forceinline__ u16 f2b(float f) {   // f32 -> bf16 RNE
    union { float f; u32 u; } v; v.f = f;
    u32 r = (v.u + 0x7fffu + ((v.u >> 16) & 1u)) >> 16;
    return (u16)r;
}

__device__ __forceinline__ short8 pack8(float4 v0, float4 v1) {
    short8 r;
    r[0] = (short)f2b(v0.x); r[1] = (short)f2b(v0.y);
    r[2] = (short)f2b(v0.z); r[3] = (short)f2b(v0.w);
    r[4] = (short)f2b(v1.x); r[5] = (short)f2b(v1.y);
    r[6] = (short)f2b(v1.z); r[7] = (short)f2b(v1.w);
    return r;
}

#define MFMA(a, b, c) __builtin_amdgcn_mfma_f32_16x16x32_bf16((a), (b), (c), 0, 0, 0)

// ---------------------------------------------------------------------------
// prep: pack weights to bf16 MFMA B-fragment order:
// frag[lane][e] = W[n0 + (lane&15)][k0 + (lane>>4)*8 + e]  (0-padded)
// ---------------------------------------------------------------------------
__global__ __launch_bounds__(256) void prep_pack(
    const float* __restrict__ Wi, const float* __restrict__ W_ih,
    const float* __restrict__ W_hh, const float* __restrict__ Wq1,
    const float* __restrict__ Wq2, const float* __restrict__ Wp1,
    const float* __restrict__ Wp2, u16* __restrict__ wp)
{
    for (size_t r = (size_t)blockIdx.x * 256 + threadIdx.x; r < P_TOTAL;
         r += (size_t)gridDim.x * 256) {
        float val = 0.f;
        if (r < P_WIH) {                           // Wi: [200 x 36]
            int tile = r / 1024, lane = (r % 1024) / 8, el = r % 8;
            int tt = tile / 2, ks = tile % 2;
            int j = tt * 16 + (lane & 15), k = ks * 32 + (lane >> 4) * 8 + el;
            if (j < 200 && k < 36 && lane < 64) val = Wi[j * 36 + k];
        } else if (r < P_WHH) {                    // W_ih
            size_t q = r - P_WIH;
            int tile = q / 1024, lane = (q % 1024) / 8, el = q % 8;
            int g = tile / 91, rem = tile % 91, tt = rem / 7, ks = rem % 7;
            int j = tt * 16 + (lane & 15), k = ks * 32 + (lane >> 4) * 8 + el;
            if (j < 200 && k < 200 && lane < 64) val = W_ih[(size_t)(g * 200 + j) * 200 + k];
        } else if (r < P_WQ1) {                    // W_hh
            size_t q = r - P_WHH;
            int tile = q / 1024, lane = (q % 1024) / 8, el = q % 8;
            int g = tile / 91, rem = tile % 91, tt = rem / 7, ks = rem % 7;
            int j = tt * 16 + (lane & 15), k = ks * 32 + (lane >> 4) * 8 + el;
            if (j < 200 && k < 200 && lane < 64) val = W_hh[(size_t)(g * 200 + j) * 200 + k];
        } else if (r < P_WQ2) {                    // Wq1[:, :200]
            size_t q = r - P_WQ1;
            int tile = q / 1024, lane = (q % 1024) / 8, el = q % 8;
            int tt = tile / 7, ks = tile % 7;
            int j = tt * 16 + (lane & 15), k = ks * 32 + (lane >> 4) * 8 + el;
            if (j < 200 && k < 200 && lane < 64) val = Wq1[(size_t)j * 1224 + k];
        } else if (r < P_EB) {                     // Wq2: [60 x 200]
            size_t q = r - P_WQ2;
            int tile = q / 1024, lane = (q % 1024) / 8, el = q % 8;
            int tt = tile / 7, ks = tile % 7;
            int j = tt * 16 + (lane & 15), k = ks * 32 + (lane >> 4) * 8 + el;
            if (j < 60 && k < 200 && lane < 64) val = Wq2[(size_t)j * 200 + k];
        } else if (r < P_WP1) {                    // epre B: Wq1[:,200:1224]
            size_t q = r - P_EB;
            int tile = q / 1024, lane = (q % 1024) / 8, el = q % 8;
            int ks = tile / 13, tt = tile % 13;
            int j = tt * 16 + (lane & 15), k = ks * 32 + (lane >> 4) * 8 + el;
            if (j < 200 && lane < 64) val = Wq1[(size_t)j * 1224 + 200 + k];
        } else if (r < P_WP2) {                    // Wp1: [200 x 200]
            size_t q = r - P_WP1;
            int tile = q / 1024, lane = (q % 1024) / 8, el = q % 8;
            int ks = tile / 13, tt = tile % 13;
            int j = tt * 16 + (lane & 15), k = ks * 32 + (lane >> 4) * 8 + el;
            if (j < 200 && k < 200 && lane < 64) val = Wp1[(size_t)j * 200 + k];
        } else {                                   // Wp2: [60 x 200]
            size_t q = r - P_WP2;
            int tile = q / 1024, lane = (q % 1024) / 8, el = q % 8;
            int ks = tile / 4, tt = tile % 4;
            int j = tt * 16 + (lane & 15), k = ks * 32 + (lane >> 4) * 8 + el;
            if (j < 60 && k < 200 && lane < 64) val = Wp2[(size_t)j * 200 + k];
        }
        wp[r] = f2b(val);
    }
}

// ---------------------------------------------------------------------------
// Epre (MFMA): out[bt*580+290+j] = embed[bt] . Wq1[j][200:] + bq1[j]
// ---------------------------------------------------------------------------
__global__ __launch_bounds__(512) void epre_mfma(
    const float* __restrict__ embed, const u16* __restrict__ wp,
    const float* __restrict__ bq1, float* __restrict__ out)
{
    const int tid = threadIdx.x;
    const int wv = tid >> 6, ln = tid & 63;
    const int arow = ln & 15, kgrp = ln >> 4;
    const int m0 = blockIdx.x * 256 + wv * 32;

    f32x4 acc[2][13];
    #pragma unroll
    for (int tt = 0; tt < 13; ++tt) {
        const int j = tt * 16 + arow;
        const float bv = (j < 200) ? bq1[j] : 0.f;
        acc[0][tt] = (f32x4){bv, bv, bv, bv};
        acc[1][tt] = acc[0][tt];
    }
    const float* e0 = &embed[(size_t)(m0 + arow) * 1024 + kgrp * 8];
    const float* e1 = e0 + (size_t)16 * 1024;

    for (int ks = 0; ks < 32; ++ks) {
        short8 a0, a1;
        {
            float4 v0 = *(const float4*)(e0 + ks * 32);
            float4 v1 = *(const float4*)(e0 + ks * 32 + 4);
            a0 = pack8(v0, v1);
            float4 w0 = *(const float4*)(e1 + ks * 32);
            float4 w1 = *(const float4*)(e1 + ks * 32 + 4);
            a1 = pack8(w0, w1);
        }
        const u16* bp = &wp[P_EB + (size_t)ks * 13 * 1024 + (size_t)ln * 8];
        #pragma unroll
        for (int tt = 0; tt < 13; ++tt) {
            short8 b = *(const short8*)(bp + (size_t)tt * 1024);
            acc[0][tt] = MFMA(a0, b, acc[0][tt]);
            acc[1][tt] = MFMA(a1, b, acc[1][tt]);
        }
    }
    #pragma unroll
    for (int f = 0; f < 2; ++f) {
        const size_t rbase = (size_t)(m0 + f * 16 + kgrp * 4);
        #pragma unroll
        for (int tt = 0; tt < 13; ++tt) {
            const int j = tt * 16 + arow;
            if (j < 200) {
                #pragma unroll
                for (int e = 0; e < 4; ++e)
                    out[(rbase + e) * OC + 290 + j] = acc[f][tt][e];
            }
        }
    }
}

// ---------------------------------------------------------------------------
// MFMA scan: 128 blocks x 8 batch rows, 512 threads (8 waves), 2 blocks/CU.
// r18 base, staging phase removed: phase C reads its 4 per-lane Epre values
// directly from out (valid: combine now writes ONLY +90..289; the +380 deter
// copy — which overlaps Epre cols 380..489 — is deferred to D2, after C).
// ---------------------------------------------------------------------------
__global__ __launch_bounds__(512, 2) void scan_mfma(
    const float* __restrict__ action, const float* __restrict__ noise_post,
    const float* __restrict__ b_ih, const float* __restrict__ b_hh,
    const float* __restrict__ bi, const float* __restrict__ bq2,
    const u16* __restrict__ wp, float* __restrict__ out)
{
    __shared__ u16   s_in0[16][72];           // [stoch30 | act6 | 0pad]
    __shared__ u16   s_x[16][SX];             // x bf16
    __shared__ u16   s_db[16][SX];            // deter bf16 (MFMA shadow)
    __shared__ u16   s_hq[16][SX];            // hq bf16
    __shared__ float s_df[RB][200];           // deter fp32 carry
    __shared__ float s_r[RB][SF], s_z[RB][SF], s_inn[RB][SF], s_hnn[RB][SF];
    __shared__ float s_q[16][64];
    __shared__ float s_bih[3][208], s_bhh[3][208], s_bi[208], s_bq2[64];

    const int tid  = threadIdx.x;
    const int wv   = tid >> 6, ln = tid & 63;
    const int arow = ln & 15, kgrp = ln >> 4;
    const int b0   = blockIdx.x * RB;
    const int ia   = tid / 6, ca = tid - (tid / 6) * 6;   // action slot (tid<48)

    // init: zero bf16 activations (incl. pad rows 8-15) + s_df, biases
    { u32* z = (u32*)s_in0; for (int i = tid; i < 16*72/2;  i += 512) z[i] = 0; }
    { u32* z = (u32*)s_x;   for (int i = tid; i < 16*SX/2;  i += 512) z[i] = 0; }
    { u32* z = (u32*)s_db;  for (int i = tid; i < 16*SX/2;  i += 512) z[i] = 0; }
    { u32* z = (u32*)s_hq;  for (int i = tid; i < 16*SX/2;  i += 512) z[i] = 0; }
    { float* z = (float*)s_df; for (int i = tid; i < RB*200; i += 512) z[i] = 0.f; }
    for (int i = tid; i < 3 * 208; i += 512) {
        int g = i / 208, j = i % 208;
        s_bih[g][j] = j < 200 ? b_ih[g * 200 + j] : 0.f;
        s_bhh[g][j] = j < 200 ? b_hh[g * 200 + j] : 0.f;
    }
    for (int i = tid; i < 208; i += 512) s_bi[i] = i < 200 ? bi[i] : 0.f;
    if (tid < 64) s_bq2[tid] = tid < 60 ? bq2[tid] : 0.f;

    // ---- persistent W_hh fragments: 5 units x 7 ks ----
    short8 whhP[5][7];
    #pragma unroll
    for (int q = 0; q < 5; ++q) {
        int p = wv + 8 * q; int pe = p < 39 ? p : 0;
        #pragma unroll
        for (int ks = 0; ks < 7; ++ks)
            whhP[q][ks] = *(const short8*)&wp[P_WHH + ((size_t)pe * 7 + ks) * 1024 + ln * 8];
    }
    __syncthreads();   // init complete before prologue staging

    // ---- prologue: stage action(0) ----
    if (tid < RB * 6)
        s_in0[ia][30 + ca] = f2b(action[((size_t)(b0 + ia) * NT + 0) * 6 + ca]);
    __syncthreads();

    for (int t = 0; t < NT; ++t) {
        const bool pN = (t + 1 < NT);

        // ---- phase A: x = elu([stoch|act] @ Wi^T + bi), 13 n-tiles ----
        for (int tt = wv; tt < 13; tt += 8) {
            float bv = s_bi[tt * 16 + arow];
            f32x4 acc = {bv, bv, bv, bv};
            #pragma unroll
            for (int ks = 0; ks < 2; ++ks) {
                short8 af = *(const short8*)&s_in0[arow][ks * 32 + kgrp * 8];
                short8 wf = *(const short8*)&wp[P_WI + (size_t)(tt * 2 + ks) * 1024 + ln * 8];
                acc = MFMA(af, wf, acc);
            }
            #pragma unroll
            for (int e = 0; e < 4; ++e)
                s_x[kgrp * 4 + e][tt * 16 + arow] = f2b(elu_f(acc[e]));
        }
        bar_lds();

        // ---- phase B: gi = x@W_ih^T (inline), gh = deter@W_hh^T (regs) ----
        {
            f32x4 gi[5], gh[5];
            #pragma unroll
            for (int q = 0; q < 5; ++q) {
                int p = wv + 8 * q; int pe = p < 39 ? p : 0;
                int g = pe / 13, tt = pe % 13;
                float b1 = s_bih[g][tt * 16 + arow];
                float b2 = s_bhh[g][tt * 16 + arow];
                gi[q] = (f32x4){b1, b1, b1, b1};
                gh[q] = (f32x4){b2, b2, b2, b2};
            }
            #pragma unroll
            for (int ks = 0; ks < 7; ++ks) {
                short8 ax = *(const short8*)&s_x[arow][ks * 32 + kgrp * 8];
                short8 ad = *(const short8*)&s_db[arow][ks * 32 + kgrp * 8];
                #pragma unroll
                for (int q = 0; q < 5; ++q) {
                    int p = wv + 8 * q; int pe = p < 39 ? p : 0;
                    short8 w1 = *(const short8*)&wp[P_WIH + ((size_t)pe * 7 + ks) * 1024 + ln * 8];
                    gi[q] = MFMA(ax, w1, gi[q]);
                    gh[q] = MFMA(ad, whhP[q][ks], gh[q]);
                }
            }
            if (kgrp < 2) {   // rows 0..7 only (f32 gate arrays are [8])
                #pragma unroll
                for (int q = 0; q < 5; ++q) {
                    int p = wv + 8 * q;
                    if (p < 39) {
                        int g = p / 13, tt = p % 13, j = tt * 16 + arow;
                        #pragma unroll
                        for (int e = 0; e < 4; ++e) {
                            int i = kgrp * 4 + e;
                            if (g == 0)      s_r[i][j] = sig_f(gi[q][e] + gh[q][e]);
                            else if (g == 1) s_z[i][j] = sig_f(gi[q][e] + gh[q][e]);
                            else { s_inn[i][j] = gi[q][e]; s_hnn[i][j] = gh[q][e]; }
                        }
                    }
                }
            }
        }
        bar_lds();

        // ---- GRU combine: deter_new; write ONLY post-deter (+90) ----
        // (+380 prior-deter overlaps Epre cols 380..489 -> deferred to D2)
        for (int idx = tid; idx < RB * 200; idx += 512) {
            int i = idx / 200, j = idx % 200;
            float rr = s_r[i][j], zz = s_z[i][j];
            float nn = tanh_f(s_inn[i][j] + rr * s_hnn[i][j]);
            float d = (1.f - zz) * nn + zz * s_df[i][j];
            s_df[i][j] = d;
            s_db[i][j] = f2b(d);
            out[((size_t)(b0 + i) * NT + t) * OC + 90 + j] = d;   // post deter
        }
        bar_lds();

        // ---- phase C: hq = elu(deter_new @ Wq1a^T + Epre-direct) ----
        float nz = 0.f, actp = 0.f;
        if (tid < RB * 30)
            nz = noise_post[((size_t)(b0 + tid / 30) * NT + t) * 30 + (tid % 30)];
        if (pN && tid < RB * 6)
            actp = action[((size_t)(b0 + ia) * NT + (t + 1)) * 6 + ca];
        for (int tt = wv; tt < 13; tt += 8) {
            int j = tt * 16 + arow;
            float ep[4];
            #pragma unroll
            for (int e = 0; e < 4; ++e) {
                int i = kgrp * 4 + e;
                // guard keeps s_hq K-pad (cols >=200) zero and avoids OOB rows
                ep[e] = (i < RB && j < 200)
                    ? out[((size_t)(b0 + i) * NT + t) * OC + 290 + j] : 0.f;
            }
            f32x4 acc = {0.f, 0.f, 0.f, 0.f};
            for (int ks = 0; ks < 7; ++ks) {
                short8 ad = *(const short8*)&s_db[arow][ks * 32 + kgrp * 8];
                short8 wf = *(const short8*)&wp[P_WQ1 + ((size_t)tt * 7 + ks) * 1024 + ln * 8];
                acc = MFMA(ad, wf, acc);
            }
            #pragma unroll
            for (int e = 0; e < 4; ++e)
                s_hq[kgrp * 4 + e][j] = f2b(elu_f(acc[e] + ep[e]));
        }
        bar_lds();

        // ---- phase D1: q = hq @ Wq2^T + bq2 (waves 0-3); prior-deter
        //      store (+380) on waves 4-7 (Epre(t) already consumed in C) ----
        if (wv < 4) {
            int tt = wv, j = tt * 16 + arow;
            float bv = s_bq2[j];
            f32x4 acc = {bv, bv, bv, bv};
            for (int ks = 0; ks < 7; ++ks) {
                short8 ah = *(const short8*)&s_hq[arow][ks * 32 + kgrp * 8];
                short8 wf = *(const short8*)&wp[P_WQ2 + ((size_t)tt * 7 + ks) * 1024 + ln * 8];
                acc = MFMA(ah, wf, acc);
            }
            #pragma unroll
            for (int e = 0; e < 4; ++e) s_q[kgrp * 4 + e][j] = acc[e];
        } else {
            const int tl = tid - 256;   // 0..255
            for (int idx = tl; idx < RB * 200; idx += 256) {
                int i = idx / 200, j = idx - i * 200;
                out[((size_t)(b0 + i) * NT + t) * OC + 380 + j] = s_df[i][j];
            }
        }
        bar_lds();

        // ---- phase D2: posterior sample + outputs + next stoch + action ----
        if (tid < RB * 30) {
            int i = tid / 30, s = tid % 30;
            float qm = s_q[i][s];
            float qs = sp_f(s_q[i][30 + s]) + 0.1f;
            size_t bt = (size_t)(b0 + i) * NT + t;
            float qst = nz * qs + qm;
            size_t o = bt * OC;
            out[o + s]      = qm;
            out[o + 30 + s] = qs;
            out[o + 60 + s] = qst;
            s_in0[i][s] = f2b(qst);
        }
        if (pN && tid < RB * 6)
            s_in0[ia][30 + ca] = f2b(actp);
        bar_lds();   // stoch/action visible before A(t+1)
    }
}

// ---------------------------------------------------------------------------
// Prior head (MFMA): 1024 blocks x 64 bt-rows, 256 thr (4 waves x 16 rows).
// ---------------------------------------------------------------------------
__global__ __launch_bounds__(256) void prior_mfma(
    const float* __restrict__ noise_prior, const u16* __restrict__ wp,
    const float* __restrict__ bp1, const float* __restrict__ bp2,
    float* __restrict__ out)
{
    __shared__ __align__(16) u16   s_hp[64][232];
    __shared__ __align__(16) float s_p[64][68];
    const int tid = threadIdx.x;
    const int wv = tid >> 6, ln = tid & 63;
    const int arow = ln & 15, kgrp = ln >> 4;
    const size_t bt0 = (size_t)blockIdx.x * 64;
    const int m0 = wv * 16;

    for (int idx = tid; idx < 64 * 32; idx += 256) {   // zero pad cols 200..231
        int r2 = idx >> 5, c = 200 + (idx & 31);
        s_hp[r2][c] = 0;
    }

    // GEMM1: hp = elu(deter @ Wp1^T + bp1)
    f32x4 acc[13];
    #pragma unroll
    for (int tt = 0; tt < 13; ++tt) {
        const int j = tt * 16 + arow;
        const float bv = (j < 200) ? bp1[j] : 0.f;
        acc[tt] = (f32x4){bv, bv, bv, bv};
    }
    for (int ks = 0; ks < 7; ++ks) {
        short8 a;
        const int k0 = ks * 32 + kgrp * 8;
        if (k0 <= 192) {
            const float* dp = &out[(bt0 + m0 + arow) * OC + 380 + k0];
            float4 v0 = *(const float4*)dp;
            float4 v1 = *(const float4*)(dp + 4);
            a = pack8(v0, v1);
        } else {
            a = (short8){0, 0, 0, 0, 0, 0, 0, 0};
        }
        const u16* bp = &wp[P_WP1 + (size_t)ks * 13 * 1024 + (size_t)ln * 8];
        #pragma unroll
        for (int tt = 0; tt < 13; ++tt)
            acc[tt] = MFMA(a, *(const short8*)(bp + (size_t)tt * 1024), acc[tt]);
    }
    #pragma unroll
    for (int tt = 0; tt < 13; ++tt)
        #pragma unroll
        for (int e = 0; e < 4; ++e)
            s_hp[m0 + kgrp * 4 + e][tt * 16 + arow] = f2b(elu_f(acc[tt][e]));
    __syncthreads();

    // GEMM2: p = hp @ Wp2^T + bp2
    f32x4 acc2[4];
    #pragma unroll
    for (int tt = 0; tt < 4; ++tt) {
        const int j = tt * 16 + arow;
        const float bv = (j < 60) ? bp2[j] : 0.f;
        acc2[tt] = (f32x4){bv, bv, bv, bv};
    }
    #pragma unroll
    for (int ks = 0; ks < 7; ++ks) {
        short8 ah = *(const short8*)&s_hp[m0 + arow][ks * 32 + kgrp * 8];
        const u16* bp = &wp[P_WP2 + (size_t)ks * 4 * 1024 + (size_t)ln * 8];
        #pragma unroll
        for (int tt = 0; tt < 4; ++tt)
            acc2[tt] = MFMA(ah, *(const short8*)(bp + (size_t)tt * 1024), acc2[tt]);
    }
    #pragma unroll
    for (int tt = 0; tt < 4; ++tt)
        #pragma unroll
        for (int e = 0; e < 4; ++e)
            s_p[m0 + kgrp * 4 + e][tt * 16 + arow] = acc2[tt][e];
    __syncthreads();

    for (int idx = tid; idx < 64 * 30; idx += 256) {
        int i = idx / 30, ss = idx - i * 30;
        float pm = s_p[i][ss];
        float ps = sp_f(s_p[i][30 + ss]) + 0.1f;
        float pst = noise_prior[(bt0 + i) * 30 + ss] * ps + pm;
        size_t base = (bt0 + i) * OC;
        out[base + 290 + ss] = pm;
        out[base + 320 + ss] = ps;
        out[base + 350 + ss] = pst;
    }
}

extern "C" void kernel_launch(void* const* d_in, const int* in_sizes, int n_in,
                              void* d_out, int out_size, void* d_ws, size_t ws_size,
                              hipStream_t stream)
{
    (void)in_sizes; (void)n_in; (void)out_size; (void)ws_size;
    const float* embed       = (const float*)d_in[0];
    const float* action      = (const float*)d_in[1];
    const float* noise_prior = (const float*)d_in[2];
    const float* noise_post  = (const float*)d_in[3];
    const float* Wi   = (const float*)d_in[4];
    const float* bi   = (const float*)d_in[5];
    const float* W_ih = (const float*)d_in[6];
    const float* W_hh = (const float*)d_in[7];
    const float* b_ih = (const float*)d_in[8];
    const float* b_hh = (const float*)d_in[9];
    const float* Wp1  = (const float*)d_in[10];
    const float* bp1  = (const float*)d_in[11];
    const float* Wp2  = (const float*)d_in[12];
    const float* bp2  = (const float*)d_in[13];
    const float* Wq1  = (const float*)d_in[14];
    const float* bq1  = (const float*)d_in[15];
    const float* Wq2  = (const float*)d_in[16];
    const float* bq2  = (const float*)d_in[17];
    float* out = (float*)d_out;
    u16* wp = (u16*)d_ws;

    hipLaunchKernelGGL(prep_pack, dim3((P_TOTAL + 255) / 256), dim3(256), 0, stream,
                       Wi, W_ih, W_hh, Wq1, Wq2, Wp1, Wp2, wp);
    hipLaunchKernelGGL(epre_mfma, dim3(256), dim3(512), 0, stream,
                       embed, wp, bq1, out);
    hipLaunchKernelGGL(scan_mfma, dim3(SCAN_BLOCKS), dim3(512), 0, stream,
                       action, noise_post, b_ih, b_hh, bi, bq2, wp, out);
    hipLaunchKernelGGL(prior_mfma, dim3(NBATCH * NT / 64), dim3(256), 0, stream,
                       noise_prior, wp, bp1, bp2, out);
}